// Round 12
// baseline (554.899 us; speedup 1.0000x reference)
//
#include <hip/hip_runtime.h>
#include <hip/hip_bf16.h>
#include <cmath>

// ToyMultiHeadAttention: B=4 T=2048 C=2048 H=16 D=128, causal.
// Pipeline: fused f32->bf16 convert | 3-seg-looped NT proj GEMM (256^2 tile,
//           4-buffer counted-vmcnt pipeline, next-seg prologue overlapped
//           with epilogue, V writes transposed) | 8-wave balanced paired
//           flash attention | NT out GEMM (256^2, f32).
// Verified-best core schedule (R5/R7). Failed probes, do not retry:
//   R6 phase-split GEMM (-7%), R8 vmcnt(0) 2-tile coarsening (-11%),
//   R9 attn KVBLK=128 (-5%), R10 256x128-tile 2-blocks/CU (-4%, +93MB fetch).
//   m201 8-phase: ledger not derivable from template summary (3 failures).

#define DEV __device__ __forceinline__

typedef short short8 __attribute__((ext_vector_type(8)));
typedef float floatx4 __attribute__((ext_vector_type(4)));

// async global->LDS, 16B per lane; LDS dest must be uniform base + lane*16
#define LDS16(gp, lp)                                                        \
  __builtin_amdgcn_global_load_lds(                                          \
      (const __attribute__((address_space(1))) void*)(gp),                   \
      (__attribute__((address_space(3))) void*)(lp), 16, 0, 0)

DEV unsigned short f2bf(float f) {  // RNE f32->bf16 (inputs finite)
  unsigned u = __builtin_bit_cast(unsigned, f);
  u += 0x7fffu + ((u >> 16) & 1u);
  return (unsigned short)(u >> 16);
}

DEV floatx4 mfma16(short8 a, short8 b, floatx4 c) {
  return __builtin_amdgcn_mfma_f32_16x16x32_bf16(a, b, c, 0, 0, 0);
}

struct Cvt7Args {
  const float* in[7];
  unsigned short* out[7];
  int n4[7];
};

__global__ __launch_bounds__(256) void cvt7_kernel(Cvt7Args a) {
  const int s = blockIdx.y;
  const float* __restrict__ in = a.in[s];
  unsigned short* __restrict__ out = a.out[s];
  const int n4 = a.n4[s];
  int stride = gridDim.x * blockDim.x;
  for (int i = blockIdx.x * blockDim.x + threadIdx.x; i < n4; i += stride) {
    float4 v = reinterpret_cast<const float4*>(in)[i];
    ushort4 o;
    o.x = f2bf(v.x); o.y = f2bf(v.y); o.z = f2bf(v.z); o.w = f2bf(v.w);
    reinterpret_cast<ushort4*>(out)[i] = o;
  }
}

// ============ 256^2-tile NT GEMM core (verified schedule) ==================
// 512 threads = 8 waves (2M x 4N). BK=32. LDS: 4 buffers x (A 16KB + B 16KB)
// = 128 KiB. Stage distance 3; one s_barrier + counted vmcnt(8) per tile
// (NEVER drain to 0 in steady state). Chunk swizzle ch ^= (row>>1)&3 on BOTH
// global source and ds_read (conflict-free). Race-freedom: stage(t+3)
// targets buf[(t-1)&3], dead since the boundary barrier after tile t-1.
DEV void gemm256_core(const unsigned short* __restrict__ aT,
                      const unsigned short* __restrict__ bT,
                      unsigned short* lds, const int K, floatx4 (&acc)[8][4]) {
  const int t = threadIdx.x;
  const int l = t & 63;
  const int w = t >> 6;
  const int wm = w >> 2, wn = w & 3;
  const int lr = l & 15, lg = l >> 4;
  const int NT = K >> 5;  // requires NT >= 3

  const int rA0 = t >> 2;
  const int chA0 = (t & 3) ^ ((rA0 >> 1) & 3);
  const int rA1 = (t + 512) >> 2;
  const int chA1 = (t & 3) ^ ((rA1 >> 1) & 3);

  auto stage = [&](int kt, int buf) {
    unsigned short* dst = lds + buf * 16384;
    const unsigned short* ga = aT + kt * 32;
    const unsigned short* gb = bT + kt * 32;
    LDS16(ga + (size_t)rA0 * K + chA0 * 8, dst + t * 8);
    LDS16(ga + (size_t)rA1 * K + chA1 * 8, dst + (t + 512) * 8);
    LDS16(gb + (size_t)rA0 * K + chA0 * 8, dst + 8192 + t * 8);
    LDS16(gb + (size_t)rA1 * K + chA1 * 8, dst + 8192 + (t + 512) * 8);
  };

  stage(0, 0);
  stage(1, 1);
  stage(2, 2);
  asm volatile("s_waitcnt vmcnt(8)" ::: "memory");
  __builtin_amdgcn_s_barrier();
  asm volatile("" ::: "memory");

  for (int tt = 0; tt < NT; ++tt) {
    const unsigned short* lA = lds + (tt & 3) * 16384;
    const unsigned short* lB = lA + 8192;
    if (tt + 3 < NT) stage(tt + 3, (tt + 3) & 3);
    short8 aF[8], bF[4];
#pragma unroll
    for (int ni = 0; ni < 4; ni++) {
      int row = wn * 64 + ni * 16 + lr;
      bF[ni] = *(const short8*)&lB[row * 32 + ((lg ^ ((row >> 1) & 3)) * 8)];
    }
#pragma unroll
    for (int mi = 0; mi < 8; mi++) {
      int row = wm * 128 + mi * 16 + lr;
      aF[mi] = *(const short8*)&lA[row * 32 + ((lg ^ ((row >> 1) & 3)) * 8)];
    }
    __builtin_amdgcn_s_setprio(1);
#pragma unroll
    for (int mi = 0; mi < 8; mi++)
#pragma unroll
      for (int ni = 0; ni < 4; ni++)
        acc[mi][ni] = mfma16(aF[mi], bF[ni], acc[mi][ni]);
    __builtin_amdgcn_s_setprio(0);
    if (tt + 1 < NT) {
      if (tt + 4 <= NT)
        asm volatile("s_waitcnt vmcnt(8)" ::: "memory");
      else if (tt + 3 == NT)
        asm volatile("s_waitcnt vmcnt(4)" ::: "memory");
      else
        asm volatile("s_waitcnt vmcnt(0)" ::: "memory");
      __builtin_amdgcn_s_barrier();
      asm volatile("" ::: "memory");
    }
  }
}

// ---- fused 3-way projection GEMM, 3 segs looped per block ----------------
// seg 0=Q(scaled) 1=K 2=V(transposed). M=8192, N=K=2048.
// Grid = 256 blocks (1/CU exactly); each block does tile (bm,bn) for all 3
// segs. Next seg's prologue stages are issued BEFORE the epilogue stores so
// staging HBM latency hides under the epilogue; seg-top uses vmcnt(0) (full
// drain of 12 stages + epilogue stores — all must land anyway) + barrier.
__global__ __launch_bounds__(512, 2) void gemm256_proj3(
    const unsigned short* __restrict__ qb, const unsigned short* __restrict__ kb,
    const unsigned short* __restrict__ vb, const unsigned short* __restrict__ wqb,
    const unsigned short* __restrict__ wkb, const unsigned short* __restrict__ wvb,
    const float* __restrict__ bq, const float* __restrict__ bk,
    const float* __restrict__ bv, unsigned short* __restrict__ Qp,
    unsigned short* __restrict__ Kp, unsigned short* __restrict__ Vt,
    float qscale) {
  constexpr int K = 2048, N = 2048;
  constexpr int NT = K >> 5;
  __shared__ unsigned short lds[65536];  // 128 KiB
  int inner = blockIdx.x;
  inner = (inner & 7) * 32 + (inner >> 3);  // XCD swizzle, 256 % 8 == 0
  const int bm = inner >> 3, bn = inner & 7;

  const int t = threadIdx.x, l = t & 63, w = t >> 6;
  const int wm = w >> 2, wn = w & 3;
  const int lr = l & 15, lg = l >> 4;
  const int rA0 = t >> 2;
  const int chA0 = (t & 3) ^ ((rA0 >> 1) & 3);
  const int rA1 = (t + 512) >> 2;
  const int chA1 = (t & 3) ^ ((rA1 >> 1) & 3);

  auto stage = [&](const unsigned short* aT, const unsigned short* bT, int kt,
                   int buf) {
    unsigned short* dst = lds + buf * 16384;
    const unsigned short* ga = aT + kt * 32;
    const unsigned short* gb = bT + kt * 32;
    LDS16(ga + (size_t)rA0 * K + chA0 * 8, dst + t * 8);
    LDS16(ga + (size_t)rA1 * K + chA1 * 8, dst + (t + 512) * 8);
    LDS16(gb + (size_t)rA0 * K + chA0 * 8, dst + 8192 + t * 8);
    LDS16(gb + (size_t)rA1 * K + chA1 * 8, dst + 8192 + (t + 512) * 8);
  };

  // prologue for seg 0
  {
    const unsigned short* aT = qb + (size_t)bm * 256 * K;
    const unsigned short* bT = wqb + (size_t)bn * 256 * K;
    stage(aT, bT, 0, 0);
    stage(aT, bT, 1, 1);
    stage(aT, bT, 2, 2);
  }

  for (int seg = 0; seg < 3; ++seg) {
    const unsigned short* A = (seg == 0) ? qb : (seg == 1) ? kb : vb;
    const unsigned short* Bw = (seg == 0) ? wqb : (seg == 1) ? wkb : wvb;
    const float* bias = (seg == 0) ? bq : (seg == 1) ? bk : bv;
    const unsigned short* aT = A + (size_t)bm * 256 * K;
    const unsigned short* bT = Bw + (size_t)bn * 256 * K;

    // seg-top wait: seg 0 = verified vmcnt(8) (12 stage-loads outstanding);
    // seg>0 = vmcnt(0) (12 stages + prior epilogue stores drain).
    if (seg == 0)
      asm volatile("s_waitcnt vmcnt(8)" ::: "memory");
    else
      asm volatile("s_waitcnt vmcnt(0)" ::: "memory");
    __builtin_amdgcn_s_barrier();
    asm volatile("" ::: "memory");

    floatx4 zero = {0.f, 0.f, 0.f, 0.f};
    floatx4 acc[8][4];
#pragma unroll
    for (int i = 0; i < 8; i++)
#pragma unroll
      for (int j = 0; j < 4; j++) acc[i][j] = zero;

    // ---- K-loop: byte-identical schedule to verified gemm256_core ----
    for (int tt = 0; tt < NT; ++tt) {
      const unsigned short* lA = lds + (tt & 3) * 16384;
      const unsigned short* lB = lA + 8192;
      if (tt + 3 < NT) stage(aT, bT, tt + 3, (tt + 3) & 3);
      short8 aF[8], bF[4];
#pragma unroll
      for (int ni = 0; ni < 4; ni++) {
        int row = wn * 64 + ni * 16 + lr;
        bF[ni] = *(const short8*)&lB[row * 32 + ((lg ^ ((row >> 1) & 3)) * 8)];
      }
#pragma unroll
      for (int mi = 0; mi < 8; mi++) {
        int row = wm * 128 + mi * 16 + lr;
        aF[mi] = *(const short8*)&lA[row * 32 + ((lg ^ ((row >> 1) & 3)) * 8)];
      }
      __builtin_amdgcn_s_setprio(1);
#pragma unroll
      for (int mi = 0; mi < 8; mi++)
#pragma unroll
        for (int ni = 0; ni < 4; ni++)
          acc[mi][ni] = mfma16(aF[mi], bF[ni], acc[mi][ni]);
      __builtin_amdgcn_s_setprio(0);
      if (tt + 1 < NT) {
        if (tt + 4 <= NT)
          asm volatile("s_waitcnt vmcnt(8)" ::: "memory");
        else if (tt + 3 == NT)
          asm volatile("s_waitcnt vmcnt(4)" ::: "memory");
        else
          asm volatile("s_waitcnt vmcnt(0)" ::: "memory");
        __builtin_amdgcn_s_barrier();
        asm volatile("" ::: "memory");
      }
    }
    __syncthreads();  // all frag reads done -> buffers dead (vmcnt already 0)

    // issue next seg's prologue BEFORE epilogue: staging overlaps stores
    if (seg < 2) {
      const unsigned short* A2 = (seg == 0) ? kb : vb;
      const unsigned short* B2 = (seg == 0) ? wkb : wvb;
      const unsigned short* aT2 = A2 + (size_t)bm * 256 * K;
      const unsigned short* bT2 = B2 + (size_t)bn * 256 * K;
      stage(aT2, bT2, 0, 0);
      stage(aT2, bT2, 1, 1);
      stage(aT2, bT2, 2, 2);
    }

    // ---- epilogue for this seg ----
    const float oscale = (seg == 0) ? qscale : 1.0f;
#pragma unroll
    for (int ni = 0; ni < 4; ni++) {
      int gc = bn * 256 + wn * 64 + ni * 16 + lr;
      float bvv = bias[gc];
#pragma unroll
      for (int mi = 0; mi < 8; mi++) {
        int gr0 = bm * 256 + wm * 128 + mi * 16 + lg * 4;
        if (seg == 2) {  // V transposed: [b][h][d][t], 4 consecutive t/lane
          int b = gr0 >> 11, tt0 = gr0 & 2047, h = gc >> 7, d = gc & 127;
          ushort4 v4;
          v4.x = f2bf(acc[mi][ni][0] + bvv);
          v4.y = f2bf(acc[mi][ni][1] + bvv);
          v4.z = f2bf(acc[mi][ni][2] + bvv);
          v4.w = f2bf(acc[mi][ni][3] + bvv);
          *(ushort4*)&Vt[((size_t)(b * 16 + h) << 18) + (d << 11) + tt0] = v4;
        } else {
          unsigned short* dst = (seg == 0) ? Qp : Kp;
#pragma unroll
          for (int r = 0; r < 4; r++)
            dst[(size_t)(gr0 + r) * N + gc] =
                f2bf((acc[mi][ni][r] + bvv) * oscale);
        }
      }
    }
  }
}

// ---- output projection GEMM, f32 out. M=8192, N=K=2048, 256 blocks. ----
__global__ __launch_bounds__(512, 2) void gemm256_out(
    const unsigned short* __restrict__ A, const unsigned short* __restrict__ Bw,
    const float* __restrict__ bias, float* __restrict__ outp) {
  constexpr int K = 2048, N = 2048;
  __shared__ unsigned short lds[65536];
  int inner = blockIdx.x;
  inner = (inner & 7) * 32 + (inner >> 3);  // XCD swizzle, 256 % 8 == 0
  const int bm = inner >> 3, bn = inner & 7;

  floatx4 zero = {0.f, 0.f, 0.f, 0.f};
  floatx4 acc[8][4];
#pragma unroll
  for (int i = 0; i < 8; i++)
#pragma unroll
    for (int j = 0; j < 4; j++) acc[i][j] = zero;

  gemm256_core(A + (size_t)bm * 256 * K, Bw + (size_t)bn * 256 * K, lds, K, acc);

  const int t = threadIdx.x, l = t & 63, w = t >> 6;
  const int wm = w >> 2, wn = w & 3;
  const int lr = l & 15, lg = l >> 4;
#pragma unroll
  for (int ni = 0; ni < 4; ni++) {
    int gc = bn * 256 + wn * 64 + ni * 16 + lr;
    float bvv = bias[gc];
#pragma unroll
    for (int mi = 0; mi < 8; mi++) {
      int gr0 = bm * 256 + wm * 128 + mi * 16 + lg * 4;
#pragma unroll
      for (int r = 0; r < 4; r++)
        outp[(size_t)(gr0 + r) * N + gc] = acc[mi][ni][r] + bvv;
    }
  }
}

// Causal flash attention, 8-wave blocks: each block = ONE bh, Q super-tile
// PAIR (x, 7-x) of 256 rows each -> uniform 36 tile-steps/block; grid 256 =
// exactly 1 block/CU (zero tail). 8 waves x 32 Q-rows, KVBLK=64, dbuf K/V
// prefetch, exp2-domain online softmax with defer-max (THR=8).
__global__ __launch_bounds__(512, 2) void attn_kernel(
    const unsigned short* __restrict__ Qp, const unsigned short* __restrict__ Kp,
    const unsigned short* __restrict__ Vt, unsigned short* __restrict__ Out) {
  constexpr int T = 2048, C = 2048;
  // ushort offsets: sK dbuf [2][64][128] @0, sV dbuf [2][128][64] @16384,
  // sP [8][32][64] @32768. Q-stage [256][128] @0 (pre-loop only).
  __shared__ unsigned short lds[49152];
  unsigned short* sP = lds + 32768;

  const int bid = blockIdx.x;
  const int swz = (bid & 7) * 32 + (bid >> 3);  // bijective, 256 % 8 == 0
  const int bh = swz >> 2;
  const int pr = swz & 3;                       // pair index 0..3
  const int b = bh >> 4, h = bh & 15;
  const int t = threadIdx.x, l = t & 63, w = t >> 6;
  const int lr = l & 15, lg = l >> 4, l7 = l & 7;

  const unsigned short* Kg = Kp + (size_t)(b * T) * C + h * 128;
  const unsigned short* Vg = Vt + ((size_t)bh << 18);  // [128][T]

  auto stage_kv = [&](int kb, int buf) {
    unsigned short* dK = lds + (buf ? 8192 : 0);
    unsigned short* dV = lds + 16384 + (buf ? 8192 : 0);
#pragma unroll
    for (int i = 0; i < 2; i++) {
      int c = t + i * 512;
      int row = c >> 4, cc = c & 15;
      LDS16(Kg + (size_t)(kb + row) * C + (cc ^ (row & 7)) * 8, &dK[c * 8]);
    }
#pragma unroll
    for (int i = 0; i < 2; i++) {
      int c = t + i * 512;
      int d = c >> 3, cc = c & 7;
      LDS16(Vg + (size_t)d * T + kb + (cc ^ (d & 7)) * 8, &dV[c * 8]);
    }
  };

  for (int seg = 0; seg < 2; seg++) {
    const int qs = seg ? pr : 7 - pr;  // heavy super-tile first
    const unsigned short* Qg = Qp + (size_t)(b * T + qs * 256) * C + h * 128;

    // ---- stage Q [256][128] into lds[0..32767], frags to regs ----
#pragma unroll
    for (int i = 0; i < 8; i++) {
      int c = t + i * 512;
      int row = c >> 4, cc = c & 15;
      LDS16(Qg + (size_t)row * C + cc * 8, &lds[c * 8]);
    }
    __syncthreads();
    const int qw = qs * 256 + w * 32;
    short8 qf[2][4];
#pragma unroll
    for (int mi = 0; mi < 2; mi++)
#pragma unroll
      for (int ks = 0; ks < 4; ks++)
        qf[mi][ks] = *(const short8*)&lds[(w * 32 + mi * 16 + lr) * 128 +
                                          ks * 32 + lg * 8];
    __syncthreads();  // all qf reads done before K/V staging overwrites

    floatx4 zero = {0.f, 0.f, 0.f, 0.f};
    floatx4 oacc[2][8];
#pragma unroll
    for (int i = 0; i < 2; i++)
#pragma unroll
      for (int j = 0; j < 8; j++) oacc[i][j] = zero;
    float mold[2][4], lsum[2][4];
#pragma unroll
    for (int i = 0; i < 2; i++)
#pragma unroll
      for (int r = 0; r < 4; r++) { mold[i][r] = -1e30f; lsum[i][r] = 0.f; }

    const int ntile = 4 * qs + 4;
    stage_kv(0, 0);
    __syncthreads();
    int cur = 0;
    for (int tile = 0; tile < ntile; tile++) {
      const int kbase = tile * 64;
      if (tile + 1 < ntile) stage_kv(kbase + 64, cur ^ 1);  // async prefetch
      const unsigned short* sK = lds + (cur ? 8192 : 0);
      const unsigned short* sV = lds + 16384 + (cur ? 8192 : 0);
      if (kbase <= qw + 31) {
        // ---- S = Q K^T ----
        floatx4 sc[2][4];
#pragma unroll
        for (int i = 0; i < 2; i++)
#pragma unroll
          for (int j = 0; j < 4; j++) sc[i][j] = zero;
        __builtin_amdgcn_s_setprio(1);
#pragma unroll
        for (int ks = 0; ks < 4; ks++) {
#pragma unroll
          for (int ni = 0; ni < 4; ni++) {
            int R = ni * 16 + lr;
            short8 bF = *(const short8*)&sK[R * 128 + ((ks * 4 + lg) ^ l7) * 8];
#pragma unroll
            for (int mi = 0; mi < 2; mi++)
              sc[mi][ni] = mfma16(qf[mi][ks], bF, sc[mi][ni]);
          }
        }
        __builtin_amdgcn_s_setprio(0);
        // ---- causal mask (diagonal tiles only) ----
        if (kbase + 63 > qw) {
#pragma unroll
          for (int mi = 0; mi < 2; mi++)
#pragma unroll
            for (int ni = 0; ni < 4; ni++)
#pragma unroll
              for (int r = 0; r < 4; r++) {
                int col = kbase + ni * 16 + lr;
                int row = qw + mi * 16 + lg * 4 + r;
                if (col > row) sc[mi][ni][r] = -1e30f;
              }
        }
        // ---- online softmax (exp2 domain, defer-max THR=8) ----
#pragma unroll
        for (int mi = 0; mi < 2; mi++) {
          float xr[4];
          int dok = 1;
#pragma unroll
          for (int r = 0; r < 4; r++) {
            float x = fmaxf(fmaxf(sc[mi][0][r], sc[mi][1][r]),
                            fmaxf(sc[mi][2][r], sc[mi][3][r]));
            x = fmaxf(x, __shfl_xor(x, 1));
            x = fmaxf(x, __shfl_xor(x, 2));
            x = fmaxf(x, __shfl_xor(x, 4));
            x = fmaxf(x, __shfl_xor(x, 8));
            xr[r] = x;
            dok &= (x - mold[mi][r] <= 8.0f) ? 1 : 0;
          }
          const bool defer = __all(dok);  // wave-uniform
          float al[4];
          if (!defer) {
#pragma unroll
            for (int r = 0; r < 4; r++) {
              float m2 = fmaxf(mold[mi][r], xr[r]);
              al[r] = __builtin_amdgcn_exp2f(mold[mi][r] - m2);
              mold[mi][r] = m2;
            }
          }
          float rs[4] = {0.f, 0.f, 0.f, 0.f};
#pragma unroll
          for (int ni = 0; ni < 4; ni++)
#pragma unroll
            for (int r = 0; r < 4; r++) {
              float p = __builtin_amdgcn_exp2f(sc[mi][ni][r] - mold[mi][r]);
              sc[mi][ni][r] = p;
              rs[r] += p;
            }
#pragma unroll
          for (int r = 0; r < 4; r++) {
            float s = rs[r];
            s += __shfl_xor(s, 1);
            s += __shfl_xor(s, 2);
            s += __shfl_xor(s, 4);
            s += __shfl_xor(s, 8);
            rs[r] = s;
          }
          if (!defer) {
#pragma unroll
            for (int r = 0; r < 4; r++)
              lsum[mi][r] = lsum[mi][r] * al[r] + rs[r];
#pragma unroll
            for (int ni = 0; ni < 8; ni++)
#pragma unroll
              for (int r = 0; r < 4; r++) oacc[mi][ni][r] *= al[r];
          } else {
#pragma unroll
            for (int r = 0; r < 4; r++) lsum[mi][r] += rs[r];
          }
          // P -> bf16 -> swizzled per-wave LDS
#pragma unroll
          for (int ni = 0; ni < 4; ni++)
#pragma unroll
            for (int r = 0; r < 4; r++) {
              int rr = mi * 16 + lg * 4 + r;
              int ch = (ni * 2 + ((l >> 3) & 1)) ^ (rr & 7);
              sP[w * 2048 + rr * 64 + ch * 8 + l7] = f2bf(sc[mi][ni][r]);
            }
        }
        // ---- O += P V ----
        __builtin_amdgcn_s_setprio(1);
#pragma unroll
        for (int ks = 0; ks < 2; ks++) {
          short8 pf[2];
#pragma unroll
          for (int mi = 0; mi < 2; mi++)
            pf[mi] = *(const short8*)&sP[w * 2048 + (mi * 16 + lr) * 64 +
                                         ((ks * 4 + lg) ^ l7) * 8];
#pragma unroll
          for (int ni = 0; ni < 8; ni++) {
            int d = ni * 16 + lr;
            short8 vF = *(const short8*)&sV[d * 64 + ((ks * 4 + lg) ^ l7) * 8];
#pragma unroll
            for (int mi = 0; mi < 2; mi++)
              oacc[mi][ni] = mfma16(pf[mi], vF, oacc[mi][ni]);
          }
        }
        __builtin_amdgcn_s_setprio(0);
      }
      __syncthreads();  // drains prefetch vmcnt; next buffer ready
      cur ^= 1;
    }
    // ---- epilogue: O/l -> bf16 row-major [B*T, C] (registers only; the
    // loop-final __syncthreads already fences LDS for next seg's Q-stage) ---
    unsigned short* Og = Out + (size_t)(b * T + qw) * C + h * 128;
#pragma unroll
    for (int mi = 0; mi < 2; mi++) {
      float rl[4];
#pragma unroll
      for (int r = 0; r < 4; r++) rl[r] = 1.0f / lsum[mi][r];
#pragma unroll
      for (int ni = 0; ni < 8; ni++)
#pragma unroll
        for (int r = 0; r < 4; r++)
          Og[(size_t)(mi * 16 + lg * 4 + r) * C + ni * 16 + lr] =
              f2bf(oacc[mi][ni][r] * rl[r]);
    }
  }
}

extern "C" void kernel_launch(void* const* d_in, const int* in_sizes, int n_in,
                              void* d_out, int out_size, void* d_ws,
                              size_t ws_size, hipStream_t stream) {
  const float* q = (const float*)d_in[0];
  const float* k = (const float*)d_in[1];
  const float* v = (const float*)d_in[2];
  const float* Wq = (const float*)d_in[3];
  const float* bq = (const float*)d_in[4];
  const float* Wk = (const float*)d_in[5];
  const float* bk = (const float*)d_in[6];
  const float* Wv = (const float*)d_in[7];
  const float* bv = (const float*)d_in[8];
  const float* Wo = (const float*)d_in[9];
  const float* bo = (const float*)d_in[10];

  const int B = 4, T = 2048, C = 2048;
  const size_t E = (size_t)B * T * C;   // 16,777,216
  const size_t WE = (size_t)C * C;      // 4,194,304
  unsigned short* ws = (unsigned short*)d_ws;
  unsigned short* qb = ws;              // bf16 q       [E]
  unsigned short* kb = ws + E;          // bf16 k
  unsigned short* vb = ws + 2 * E;      // bf16 v
  unsigned short* wqb = ws + 3 * E;     // bf16 weights [WE] x4
  unsigned short* wkb = wqb + WE;
  unsigned short* wvb = wqb + 2 * WE;
  unsigned short* wob = wqb + 3 * WE;
  unsigned short* Qp = ws + 4 * E;      // projected Q (pre-scaled)
  unsigned short* Kp = ws + 5 * E;      // projected K
  unsigned short* Vtb = ws + 6 * E;     // projected V, [B,H,D,T]
  unsigned short* attn = qb;            // alias: qb dead after projections
  // total workspace: 7*E*2 = 234,881,024 bytes

  Cvt7Args ca;
  ca.in[0] = q;  ca.out[0] = qb;  ca.n4[0] = (int)(E / 4);
  ca.in[1] = k;  ca.out[1] = kb;  ca.n4[1] = (int)(E / 4);
  ca.in[2] = v;  ca.out[2] = vb;  ca.n4[2] = (int)(E / 4);
  ca.in[3] = Wq; ca.out[3] = wqb; ca.n4[3] = (int)(WE / 4);
  ca.in[4] = Wk; ca.out[4] = wkb; ca.n4[4] = (int)(WE / 4);
  ca.in[5] = Wv; ca.out[5] = wvb; ca.n4[5] = (int)(WE / 4);
  ca.in[6] = Wo; ca.out[6] = wob; ca.n4[6] = (int)(WE / 4);
  cvt7_kernel<<<dim3(512, 7), 256, 0, stream>>>(ca);

  const float qscale = 1.4426950408889634f / sqrtf(128.0f);  // log2e/sqrt(D)
  gemm256_proj3<<<256, 512, 0, stream>>>(qb, kb, vb, wqb, wkb, wvb, bq, bk, bv,
                                         Qp, Kp, Vtb, qscale);

  attn_kernel<<<256, 512, 0, stream>>>(Qp, Kp, Vtb, attn);

  gemm256_out<<<256, 512, 0, stream>>>(attn, wob, bo, (float*)d_out);
}

// Round 13
// 528.297 us; speedup vs baseline: 1.0504x; 1.0504x over previous
//
#include <hip/hip_runtime.h>
#include <hip/hip_bf16.h>
#include <cmath>

// ToyMultiHeadAttention: B=4 T=2048 C=2048 H=16 D=128, causal.
// Pipeline: fused f32->bf16 convert | fused 3x NT proj GEMM (256^2 tile,
//           4-buffer counted-vmcnt pipeline, V writes transposed) |
//           8-wave balanced paired flash attention | NT out GEMM (256^2, f32).
// R11-verified best configuration (529us). Failed probes, do not retry:
//   R6 phase-split GEMM (-7%), R8 vmcnt(0) 2-tile coarsening (-11%),
//   R9 attn KVBLK=128 (-5%), R10 256x128-tile 2-blocks/CU (-4%, +93MB fetch),
//   R12 seg-looped proj3 (-12%: +32 VGPR, +36MB fetch — concurrent dispatch
//   shares weight panels in L2 better than per-block serial segs).

#define DEV __device__ __forceinline__

typedef short short8 __attribute__((ext_vector_type(8)));
typedef float floatx4 __attribute__((ext_vector_type(4)));

// async global->LDS, 16B per lane; LDS dest must be uniform base + lane*16
#define LDS16(gp, lp)                                                        \
  __builtin_amdgcn_global_load_lds(                                          \
      (const __attribute__((address_space(1))) void*)(gp),                   \
      (__attribute__((address_space(3))) void*)(lp), 16, 0, 0)

DEV unsigned short f2bf(float f) {  // RNE f32->bf16 (inputs finite)
  unsigned u = __builtin_bit_cast(unsigned, f);
  u += 0x7fffu + ((u >> 16) & 1u);
  return (unsigned short)(u >> 16);
}

DEV floatx4 mfma16(short8 a, short8 b, floatx4 c) {
  return __builtin_amdgcn_mfma_f32_16x16x32_bf16(a, b, c, 0, 0, 0);
}

struct Cvt7Args {
  const float* in[7];
  unsigned short* out[7];
  int n4[7];
};

__global__ __launch_bounds__(256) void cvt7_kernel(Cvt7Args a) {
  const int s = blockIdx.y;
  const float* __restrict__ in = a.in[s];
  unsigned short* __restrict__ out = a.out[s];
  const int n4 = a.n4[s];
  int stride = gridDim.x * blockDim.x;
  for (int i = blockIdx.x * blockDim.x + threadIdx.x; i < n4; i += stride) {
    float4 v = reinterpret_cast<const float4*>(in)[i];
    ushort4 o;
    o.x = f2bf(v.x); o.y = f2bf(v.y); o.z = f2bf(v.z); o.w = f2bf(v.w);
    reinterpret_cast<ushort4*>(out)[i] = o;
  }
}

// ============ 256^2-tile NT GEMM core: C[256,256] = A[256,K] * B[256,K]^T ===
// 512 threads = 8 waves (2M x 4N). BK=32. LDS: 4 buffers x (A 16KB + B 16KB)
// = 128 KiB. Stage distance 3 tiles; one s_barrier + counted vmcnt(8) per
// tile (NEVER drain to 0 in steady state).
// LDS chunk swizzle ch ^= (row>>1)&3 on BOTH global source and ds_read
// (conflict-free: (row&1,(row>>1)&3) injective over 8 consecutive rows).
// Race-freedom: stage(t+3) targets buf[(t-1)&3], dead since the boundary
// barrier after tile t-1. Boundary after tile t: vmcnt(8) = stages(t+2,t+3)
// outstanding => stage(t+1) landed.
DEV void gemm256_core(const unsigned short* __restrict__ aT,
                      const unsigned short* __restrict__ bT,
                      unsigned short* lds, const int K, floatx4 (&acc)[8][4]) {
  const int t = threadIdx.x;
  const int l = t & 63;
  const int w = t >> 6;
  const int wm = w >> 2, wn = w & 3;
  const int lr = l & 15, lg = l >> 4;
  const int NT = K >> 5;  // requires NT >= 3

  // staging: A tile 256x32 = 1024 16B-chunks, 2 per thread; same for B.
  const int rA0 = t >> 2;
  const int chA0 = (t & 3) ^ ((rA0 >> 1) & 3);
  const int rA1 = (t + 512) >> 2;
  const int chA1 = (t & 3) ^ ((rA1 >> 1) & 3);

  auto stage = [&](int kt, int buf) {
    unsigned short* dst = lds + buf * 16384;
    const unsigned short* ga = aT + kt * 32;
    const unsigned short* gb = bT + kt * 32;
    LDS16(ga + (size_t)rA0 * K + chA0 * 8, dst + t * 8);
    LDS16(ga + (size_t)rA1 * K + chA1 * 8, dst + (t + 512) * 8);
    LDS16(gb + (size_t)rA0 * K + chA0 * 8, dst + 8192 + t * 8);
    LDS16(gb + (size_t)rA1 * K + chA1 * 8, dst + 8192 + (t + 512) * 8);
  };

  // prologue: tiles 0,1,2 in flight; wait tile 0 (oldest 4 of 12 loads)
  stage(0, 0);
  stage(1, 1);
  stage(2, 2);
  asm volatile("s_waitcnt vmcnt(8)" ::: "memory");
  __builtin_amdgcn_s_barrier();
  asm volatile("" ::: "memory");

  for (int tt = 0; tt < NT; ++tt) {
    const unsigned short* lA = lds + (tt & 3) * 16384;
    const unsigned short* lB = lA + 8192;
    if (tt + 3 < NT) stage(tt + 3, (tt + 3) & 3);  // into buf[(tt-1)&3]
    short8 aF[8], bF[4];
#pragma unroll
    for (int ni = 0; ni < 4; ni++) {
      int row = wn * 64 + ni * 16 + lr;
      bF[ni] = *(const short8*)&lB[row * 32 + ((lg ^ ((row >> 1) & 3)) * 8)];
    }
#pragma unroll
    for (int mi = 0; mi < 8; mi++) {
      int row = wm * 128 + mi * 16 + lr;
      aF[mi] = *(const short8*)&lA[row * 32 + ((lg ^ ((row >> 1) & 3)) * 8)];
    }
    __builtin_amdgcn_s_setprio(1);
#pragma unroll
    for (int mi = 0; mi < 8; mi++)
#pragma unroll
      for (int ni = 0; ni < 4; ni++)
        acc[mi][ni] = mfma16(aF[mi], bF[ni], acc[mi][ni]);
    __builtin_amdgcn_s_setprio(0);
    if (tt + 1 < NT) {  // boundary: ensure tile tt+1 resident for next iter
      if (tt + 4 <= NT)
        asm volatile("s_waitcnt vmcnt(8)" ::: "memory");
      else if (tt + 3 == NT)
        asm volatile("s_waitcnt vmcnt(4)" ::: "memory");
      else
        asm volatile("s_waitcnt vmcnt(0)" ::: "memory");
      __builtin_amdgcn_s_barrier();
      asm volatile("" ::: "memory");
    }
  }
}

// ---- fused 3-way projection GEMM: seg 0=Q(scaled) 1=K 2=V(transposed) ----
// M=8192, N=K=2048. Grid = 3 * 256 blocks of 512 threads.
__global__ __launch_bounds__(512, 2) void gemm256_proj3(
    const unsigned short* __restrict__ qb, const unsigned short* __restrict__ kb,
    const unsigned short* __restrict__ vb, const unsigned short* __restrict__ wqb,
    const unsigned short* __restrict__ wkb, const unsigned short* __restrict__ wvb,
    const float* __restrict__ bq, const float* __restrict__ bk,
    const float* __restrict__ bv, unsigned short* __restrict__ Qp,
    unsigned short* __restrict__ Kp, unsigned short* __restrict__ Vt,
    float qscale) {
  constexpr int K = 2048, N = 2048;
  __shared__ unsigned short lds[65536];  // 128 KiB
  const int seg = blockIdx.x >> 8;
  int inner = blockIdx.x & 255;
  inner = (inner & 7) * 32 + (inner >> 3);  // XCD swizzle, 256 % 8 == 0
  const int bm = inner >> 3, bn = inner & 7;

  const unsigned short* A = (seg == 0) ? qb : (seg == 1) ? kb : vb;
  const unsigned short* Bw = (seg == 0) ? wqb : (seg == 1) ? wkb : wvb;
  const float* bias = (seg == 0) ? bq : (seg == 1) ? bk : bv;

  floatx4 zero = {0.f, 0.f, 0.f, 0.f};
  floatx4 acc[8][4];
#pragma unroll
  for (int i = 0; i < 8; i++)
#pragma unroll
    for (int j = 0; j < 4; j++) acc[i][j] = zero;

  gemm256_core(A + (size_t)bm * 256 * K, Bw + (size_t)bn * 256 * K, lds, K, acc);

  const int t = threadIdx.x, l = t & 63, w = t >> 6;
  const int wm = w >> 2, wn = w & 3;
  const int lr = l & 15, lg = l >> 4;
  const float oscale = (seg == 0) ? qscale : 1.0f;
#pragma unroll
  for (int ni = 0; ni < 4; ni++) {
    int gc = bn * 256 + wn * 64 + ni * 16 + lr;
    float bvv = bias[gc];
#pragma unroll
    for (int mi = 0; mi < 8; mi++) {
      int gr0 = bm * 256 + wm * 128 + mi * 16 + lg * 4;
      if (seg == 2) {  // V transposed: [b][h][d][t], 4 consecutive t per lane
        int b = gr0 >> 11, tt0 = gr0 & 2047, h = gc >> 7, d = gc & 127;
        ushort4 v4;
        v4.x = f2bf(acc[mi][ni][0] + bvv);
        v4.y = f2bf(acc[mi][ni][1] + bvv);
        v4.z = f2bf(acc[mi][ni][2] + bvv);
        v4.w = f2bf(acc[mi][ni][3] + bvv);
        *(ushort4*)&Vt[((size_t)(b * 16 + h) << 18) + (d << 11) + tt0] = v4;
      } else {
        unsigned short* dst = (seg == 0) ? Qp : Kp;
#pragma unroll
        for (int r = 0; r < 4; r++)
          dst[(size_t)(gr0 + r) * N + gc] =
              f2bf((acc[mi][ni][r] + bvv) * oscale);
      }
    }
  }
}

// ---- output projection GEMM, f32 out. M=8192, N=K=2048, 256 blocks. ----
__global__ __launch_bounds__(512, 2) void gemm256_out(
    const unsigned short* __restrict__ A, const unsigned short* __restrict__ Bw,
    const float* __restrict__ bias, float* __restrict__ outp) {
  constexpr int K = 2048, N = 2048;
  __shared__ unsigned short lds[65536];
  int inner = blockIdx.x;
  inner = (inner & 7) * 32 + (inner >> 3);  // XCD swizzle, 256 % 8 == 0
  const int bm = inner >> 3, bn = inner & 7;

  floatx4 zero = {0.f, 0.f, 0.f, 0.f};
  floatx4 acc[8][4];
#pragma unroll
  for (int i = 0; i < 8; i++)
#pragma unroll
    for (int j = 0; j < 4; j++) acc[i][j] = zero;

  gemm256_core(A + (size_t)bm * 256 * K, Bw + (size_t)bn * 256 * K, lds, K, acc);

  const int t = threadIdx.x, l = t & 63, w = t >> 6;
  const int wm = w >> 2, wn = w & 3;
  const int lr = l & 15, lg = l >> 4;
#pragma unroll
  for (int ni = 0; ni < 4; ni++) {
    int gc = bn * 256 + wn * 64 + ni * 16 + lr;
    float bvv = bias[gc];
#pragma unroll
    for (int mi = 0; mi < 8; mi++) {
      int gr0 = bm * 256 + wm * 128 + mi * 16 + lg * 4;
#pragma unroll
      for (int r = 0; r < 4; r++)
        outp[(size_t)(gr0 + r) * N + gc] = acc[mi][ni][r] + bvv;
    }
  }
}

// Causal flash attention, 8-wave blocks: each block = ONE bh, Q super-tile
// PAIR (x, 7-x) of 256 rows each -> uniform 36 tile-steps/block; grid 256 =
// exactly 1 block/CU (zero tail). 8 waves x 32 Q-rows, KVBLK=64, dbuf K/V
// prefetch, exp2-domain online softmax with defer-max (THR=8).
__global__ __launch_bounds__(512, 2) void attn_kernel(
    const unsigned short* __restrict__ Qp, const unsigned short* __restrict__ Kp,
    const unsigned short* __restrict__ Vt, unsigned short* __restrict__ Out) {
  constexpr int T = 2048, C = 2048;
  // ushort offsets: sK dbuf [2][64][128] @0, sV dbuf [2][128][64] @16384,
  // sP [8][32][64] @32768. Q-stage [256][128] @0 (pre-loop only).
  __shared__ unsigned short lds[49152];
  unsigned short* sP = lds + 32768;

  const int bid = blockIdx.x;
  const int swz = (bid & 7) * 32 + (bid >> 3);  // bijective, 256 % 8 == 0
  const int bh = swz >> 2;
  const int pr = swz & 3;                       // pair index 0..3
  const int b = bh >> 4, h = bh & 15;
  const int t = threadIdx.x, l = t & 63, w = t >> 6;
  const int lr = l & 15, lg = l >> 4, l7 = l & 7;

  const unsigned short* Kg = Kp + (size_t)(b * T) * C + h * 128;
  const unsigned short* Vg = Vt + ((size_t)bh << 18);  // [128][T]

  auto stage_kv = [&](int kb, int buf) {
    unsigned short* dK = lds + (buf ? 8192 : 0);
    unsigned short* dV = lds + 16384 + (buf ? 8192 : 0);
#pragma unroll
    for (int i = 0; i < 2; i++) {
      int c = t + i * 512;
      int row = c >> 4, cc = c & 15;
      LDS16(Kg + (size_t)(kb + row) * C + (cc ^ (row & 7)) * 8, &dK[c * 8]);
    }
#pragma unroll
    for (int i = 0; i < 2; i++) {
      int c = t + i * 512;
      int d = c >> 3, cc = c & 7;
      LDS16(Vg + (size_t)d * T + kb + (cc ^ (d & 7)) * 8, &dV[c * 8]);
    }
  };

  for (int seg = 0; seg < 2; seg++) {
    const int qs = seg ? pr : 7 - pr;  // heavy super-tile first
    const unsigned short* Qg = Qp + (size_t)(b * T + qs * 256) * C + h * 128;

    // ---- stage Q [256][128] into lds[0..32767], frags to regs ----
#pragma unroll
    for (int i = 0; i < 8; i++) {
      int c = t + i * 512;
      int row = c >> 4, cc = c & 15;
      LDS16(Qg + (size_t)row * C + cc * 8, &lds[c * 8]);
    }
    __syncthreads();
    const int qw = qs * 256 + w * 32;
    short8 qf[2][4];
#pragma unroll
    for (int mi = 0; mi < 2; mi++)
#pragma unroll
      for (int ks = 0; ks < 4; ks++)
        qf[mi][ks] = *(const short8*)&lds[(w * 32 + mi * 16 + lr) * 128 +
                                          ks * 32 + lg * 8];
    __syncthreads();  // all qf reads done before K/V staging overwrites

    floatx4 zero = {0.f, 0.f, 0.f, 0.f};
    floatx4 oacc[2][8];
#pragma unroll
    for (int i = 0; i < 2; i++)
#pragma unroll
      for (int j = 0; j < 8; j++) oacc[i][j] = zero;
    float mold[2][4], lsum[2][4];
#pragma unroll
    for (int i = 0; i < 2; i++)
#pragma unroll
      for (int r = 0; r < 4; r++) { mold[i][r] = -1e30f; lsum[i][r] = 0.f; }

    const int ntile = 4 * qs + 4;
    stage_kv(0, 0);
    __syncthreads();
    int cur = 0;
    for (int tile = 0; tile < ntile; tile++) {
      const int kbase = tile * 64;
      if (tile + 1 < ntile) stage_kv(kbase + 64, cur ^ 1);  // async prefetch
      const unsigned short* sK = lds + (cur ? 8192 : 0);
      const unsigned short* sV = lds + 16384 + (cur ? 8192 : 0);
      if (kbase <= qw + 31) {
        // ---- S = Q K^T ----
        floatx4 sc[2][4];
#pragma unroll
        for (int i = 0; i < 2; i++)
#pragma unroll
          for (int j = 0; j < 4; j++) sc[i][j] = zero;
        __builtin_amdgcn_s_setprio(1);
#pragma unroll
        for (int ks = 0; ks < 4; ks++) {
#pragma unroll
          for (int ni = 0; ni < 4; ni++) {
            int R = ni * 16 + lr;
            short8 bF = *(const short8*)&sK[R * 128 + ((ks * 4 + lg) ^ l7) * 8];
#pragma unroll
            for (int mi = 0; mi < 2; mi++)
              sc[mi][ni] = mfma16(qf[mi][ks], bF, sc[mi][ni]);
          }
        }
        __builtin_amdgcn_s_setprio(0);
        // ---- causal mask (diagonal tiles only) ----
        if (kbase + 63 > qw) {
#pragma unroll
          for (int mi = 0; mi < 2; mi++)
#pragma unroll
            for (int ni = 0; ni < 4; ni++)
#pragma unroll
              for (int r = 0; r < 4; r++) {
                int col = kbase + ni * 16 + lr;
                int row = qw + mi * 16 + lg * 4 + r;
                if (col > row) sc[mi][ni][r] = -1e30f;
              }
        }
        // ---- online softmax (exp2 domain, defer-max THR=8) ----
#pragma unroll
        for (int mi = 0; mi < 2; mi++) {
          float xr[4];
          int dok = 1;
#pragma unroll
          for (int r = 0; r < 4; r++) {
            float x = fmaxf(fmaxf(sc[mi][0][r], sc[mi][1][r]),
                            fmaxf(sc[mi][2][r], sc[mi][3][r]));
            x = fmaxf(x, __shfl_xor(x, 1));
            x = fmaxf(x, __shfl_xor(x, 2));
            x = fmaxf(x, __shfl_xor(x, 4));
            x = fmaxf(x, __shfl_xor(x, 8));
            xr[r] = x;
            dok &= (x - mold[mi][r] <= 8.0f) ? 1 : 0;
          }
          const bool defer = __all(dok);  // wave-uniform
          float al[4];
          if (!defer) {
#pragma unroll
            for (int r = 0; r < 4; r++) {
              float m2 = fmaxf(mold[mi][r], xr[r]);
              al[r] = __builtin_amdgcn_exp2f(mold[mi][r] - m2);
              mold[mi][r] = m2;
            }
          }
          float rs[4] = {0.f, 0.f, 0.f, 0.f};
#pragma unroll
          for (int ni = 0; ni < 4; ni++)
#pragma unroll
            for (int r = 0; r < 4; r++) {
              float p = __builtin_amdgcn_exp2f(sc[mi][ni][r] - mold[mi][r]);
              sc[mi][ni][r] = p;
              rs[r] += p;
            }
#pragma unroll
          for (int r = 0; r < 4; r++) {
            float s = rs[r];
            s += __shfl_xor(s, 1);
            s += __shfl_xor(s, 2);
            s += __shfl_xor(s, 4);
            s += __shfl_xor(s, 8);
            rs[r] = s;
          }
          if (!defer) {
#pragma unroll
            for (int r = 0; r < 4; r++)
              lsum[mi][r] = lsum[mi][r] * al[r] + rs[r];
#pragma unroll
            for (int ni = 0; ni < 8; ni++)
#pragma unroll
              for (int r = 0; r < 4; r++) oacc[mi][ni][r] *= al[r];
          } else {
#pragma unroll
            for (int r = 0; r < 4; r++) lsum[mi][r] += rs[r];
          }
          // P -> bf16 -> swizzled per-wave LDS
#pragma unroll
          for (int ni = 0; ni < 4; ni++)
#pragma unroll
            for (int r = 0; r < 4; r++) {
              int rr = mi * 16 + lg * 4 + r;
              int ch = (ni * 2 + ((l >> 3) & 1)) ^ (rr & 7);
              sP[w * 2048 + rr * 64 + ch * 8 + l7] = f2bf(sc[mi][ni][r]);
            }
        }
        // ---- O += P V ----
        __builtin_amdgcn_s_setprio(1);
#pragma unroll
        for (int ks = 0; ks < 2; ks++) {
          short8 pf[2];
#pragma unroll
          for (int mi = 0; mi < 2; mi++)
            pf[mi] = *(const short8*)&sP[w * 2048 + (mi * 16 + lr) * 64 +
                                         ((ks * 4 + lg) ^ l7) * 8];
#pragma unroll
          for (int ni = 0; ni < 8; ni++) {
            int d = ni * 16 + lr;
            short8 vF = *(const short8*)&sV[d * 64 + ((ks * 4 + lg) ^ l7) * 8];
#pragma unroll
            for (int mi = 0; mi < 2; mi++)
              oacc[mi][ni] = mfma16(pf[mi], vF, oacc[mi][ni]);
          }
        }
        __builtin_amdgcn_s_setprio(0);
      }
      __syncthreads();  // drains prefetch vmcnt; next buffer ready
      cur ^= 1;
    }
    // ---- epilogue: O/l -> bf16 row-major [B*T, C] (registers only; the
    // loop-final __syncthreads already fences LDS for next seg's Q-stage) ---
    unsigned short* Og = Out + (size_t)(b * T + qw) * C + h * 128;
#pragma unroll
    for (int mi = 0; mi < 2; mi++) {
      float rl[4];
#pragma unroll
      for (int r = 0; r < 4; r++) rl[r] = 1.0f / lsum[mi][r];
#pragma unroll
      for (int ni = 0; ni < 8; ni++)
#pragma unroll
        for (int r = 0; r < 4; r++)
          Og[(size_t)(mi * 16 + lg * 4 + r) * C + ni * 16 + lr] =
              f2bf(oacc[mi][ni][r] * rl[r]);
    }
  }
}

extern "C" void kernel_launch(void* const* d_in, const int* in_sizes, int n_in,
                              void* d_out, int out_size, void* d_ws,
                              size_t ws_size, hipStream_t stream) {
  const float* q = (const float*)d_in[0];
  const float* k = (const float*)d_in[1];
  const float* v = (const float*)d_in[2];
  const float* Wq = (const float*)d_in[3];
  const float* bq = (const float*)d_in[4];
  const float* Wk = (const float*)d_in[5];
  const float* bk = (const float*)d_in[6];
  const float* Wv = (const float*)d_in[7];
  const float* bv = (const float*)d_in[8];
  const float* Wo = (const float*)d_in[9];
  const float* bo = (const float*)d_in[10];

  const int B = 4, T = 2048, C = 2048;
  const size_t E = (size_t)B * T * C;   // 16,777,216
  const size_t WE = (size_t)C * C;      // 4,194,304
  unsigned short* ws = (unsigned short*)d_ws;
  unsigned short* qb = ws;              // bf16 q       [E]
  unsigned short* kb = ws + E;          // bf16 k
  unsigned short* vb = ws + 2 * E;      // bf16 v
  unsigned short* wqb = ws + 3 * E;     // bf16 weights [WE] x4
  unsigned short* wkb = wqb + WE;
  unsigned short* wvb = wqb + 2 * WE;
  unsigned short* wob = wqb + 3 * WE;
  unsigned short* Qp = ws + 4 * E;      // projected Q (pre-scaled)
  unsigned short* Kp = ws + 5 * E;      // projected K
  unsigned short* Vtb = ws + 6 * E;     // projected V, [B,H,D,T]
  unsigned short* attn = qb;            // alias: qb dead after projections
  // total workspace: 7*E*2 = 234,881,024 bytes

  Cvt7Args ca;
  ca.in[0] = q;  ca.out[0] = qb;  ca.n4[0] = (int)(E / 4);
  ca.in[1] = k;  ca.out[1] = kb;  ca.n4[1] = (int)(E / 4);
  ca.in[2] = v;  ca.out[2] = vb;  ca.n4[2] = (int)(E / 4);
  ca.in[3] = Wq; ca.out[3] = wqb; ca.n4[3] = (int)(WE / 4);
  ca.in[4] = Wk; ca.out[4] = wkb; ca.n4[4] = (int)(WE / 4);
  ca.in[5] = Wv; ca.out[5] = wvb; ca.n4[5] = (int)(WE / 4);
  ca.in[6] = Wo; ca.out[6] = wob; ca.n4[6] = (int)(WE / 4);
  cvt7_kernel<<<dim3(512, 7), 256, 0, stream>>>(ca);

  const float qscale = 1.4426950408889634f / sqrtf(128.0f);  // log2e/sqrt(D)
  gemm256_proj3<<<768, 512, 0, stream>>>(qb, kb, vb, wqb, wkb, wvb, bq, bk, bv,
                                         Qp, Kp, Vtb, qscale);

  attn_kernel<<<256, 512, 0, stream>>>(Qp, Kp, Vtb, attn);

  gemm256_out<<<256, 512, 0, stream>>>(attn, wob, bo, (float*)d_out);
}

// Round 14
// 512.472 us; speedup vs baseline: 1.0828x; 1.0309x over previous
//
#include <hip/hip_runtime.h>
#include <hip/hip_bf16.h>
#include <cmath>

// ToyMultiHeadAttention: B=4 T=2048 C=2048 H=16 D=128, causal.
// Pipeline: fused f32->bf16 convert | fused 3x NT proj GEMM (256^2 tile,
//           4-buffer counted-vmcnt pipeline, LDS-coalesced epilogue,
//           V writes transposed) | 8-wave balanced paired flash attention |
//           NT out GEMM (256^2, f32).
// Base = R11-verified best (529us). Failed probes, do not retry:
//   R6 phase-split GEMM (-7%), R8 vmcnt(0) 2-tile coarsening (-11%),
//   R9 attn KVBLK=128 (-5%), R10 256x128-tile 2-blocks/CU (-4%, +93MB fetch),
//   R12 seg-looped proj3 (-12%: +32 VGPR, lost cross-block L2 sharing).
// R13 change: proj3 epilogue via LDS -> coalesced 16B stores (WRITE_SIZE
//   counter showed 194MB vs 96MB ideal = 2x partial-line amplification).

#define DEV __device__ __forceinline__

typedef short short8 __attribute__((ext_vector_type(8)));
typedef float floatx4 __attribute__((ext_vector_type(4)));

// async global->LDS, 16B per lane; LDS dest must be uniform base + lane*16
#define LDS16(gp, lp)                                                        \
  __builtin_amdgcn_global_load_lds(                                          \
      (const __attribute__((address_space(1))) void*)(gp),                   \
      (__attribute__((address_space(3))) void*)(lp), 16, 0, 0)

DEV unsigned short f2bf(float f) {  // RNE f32->bf16 (inputs finite)
  unsigned u = __builtin_bit_cast(unsigned, f);
  u += 0x7fffu + ((u >> 16) & 1u);
  return (unsigned short)(u >> 16);
}

DEV floatx4 mfma16(short8 a, short8 b, floatx4 c) {
  return __builtin_amdgcn_mfma_f32_16x16x32_bf16(a, b, c, 0, 0, 0);
}

struct Cvt7Args {
  const float* in[7];
  unsigned short* out[7];
  int n4[7];
};

__global__ __launch_bounds__(256) void cvt7_kernel(Cvt7Args a) {
  const int s = blockIdx.y;
  const float* __restrict__ in = a.in[s];
  unsigned short* __restrict__ out = a.out[s];
  const int n4 = a.n4[s];
  int stride = gridDim.x * blockDim.x;
  for (int i = blockIdx.x * blockDim.x + threadIdx.x; i < n4; i += stride) {
    float4 v = reinterpret_cast<const float4*>(in)[i];
    ushort4 o;
    o.x = f2bf(v.x); o.y = f2bf(v.y); o.z = f2bf(v.z); o.w = f2bf(v.w);
    reinterpret_cast<ushort4*>(out)[i] = o;
  }
}

// ============ 256^2-tile NT GEMM core: C[256,256] = A[256,K] * B[256,K]^T ===
// 512 threads = 8 waves (2M x 4N). BK=32. LDS: 4 buffers x (A 16KB + B 16KB)
// = 128 KiB. Stage distance 3 tiles; one s_barrier + counted vmcnt(8) per
// tile (NEVER drain to 0 in steady state).
// LDS chunk swizzle ch ^= (row>>1)&3 on BOTH global source and ds_read
// (conflict-free: (row&1,(row>>1)&3) injective over 8 consecutive rows).
// Race-freedom: stage(t+3) targets buf[(t-1)&3], dead since the boundary
// barrier after tile t-1. Boundary after tile t: vmcnt(8) = stages(t+2,t+3)
// outstanding => stage(t+1) landed. On exit vmcnt==0 (the tt+2==NT boundary
// drained the final stage).
DEV void gemm256_core(const unsigned short* __restrict__ aT,
                      const unsigned short* __restrict__ bT,
                      unsigned short* lds, const int K, floatx4 (&acc)[8][4]) {
  const int t = threadIdx.x;
  const int l = t & 63;
  const int w = t >> 6;
  const int wm = w >> 2, wn = w & 3;
  const int lr = l & 15, lg = l >> 4;
  const int NT = K >> 5;  // requires NT >= 3

  // staging: A tile 256x32 = 1024 16B-chunks, 2 per thread; same for B.
  const int rA0 = t >> 2;
  const int chA0 = (t & 3) ^ ((rA0 >> 1) & 3);
  const int rA1 = (t + 512) >> 2;
  const int chA1 = (t & 3) ^ ((rA1 >> 1) & 3);

  auto stage = [&](int kt, int buf) {
    unsigned short* dst = lds + buf * 16384;
    const unsigned short* ga = aT + kt * 32;
    const unsigned short* gb = bT + kt * 32;
    LDS16(ga + (size_t)rA0 * K + chA0 * 8, dst + t * 8);
    LDS16(ga + (size_t)rA1 * K + chA1 * 8, dst + (t + 512) * 8);
    LDS16(gb + (size_t)rA0 * K + chA0 * 8, dst + 8192 + t * 8);
    LDS16(gb + (size_t)rA1 * K + chA1 * 8, dst + 8192 + (t + 512) * 8);
  };

  // prologue: tiles 0,1,2 in flight; wait tile 0 (oldest 4 of 12 loads)
  stage(0, 0);
  stage(1, 1);
  stage(2, 2);
  asm volatile("s_waitcnt vmcnt(8)" ::: "memory");
  __builtin_amdgcn_s_barrier();
  asm volatile("" ::: "memory");

  for (int tt = 0; tt < NT; ++tt) {
    const unsigned short* lA = lds + (tt & 3) * 16384;
    const unsigned short* lB = lA + 8192;
    if (tt + 3 < NT) stage(tt + 3, (tt + 3) & 3);  // into buf[(tt-1)&3]
    short8 aF[8], bF[4];
#pragma unroll
    for (int ni = 0; ni < 4; ni++) {
      int row = wn * 64 + ni * 16 + lr;
      bF[ni] = *(const short8*)&lB[row * 32 + ((lg ^ ((row >> 1) & 3)) * 8)];
    }
#pragma unroll
    for (int mi = 0; mi < 8; mi++) {
      int row = wm * 128 + mi * 16 + lr;
      aF[mi] = *(const short8*)&lA[row * 32 + ((lg ^ ((row >> 1) & 3)) * 8)];
    }
    __builtin_amdgcn_s_setprio(1);
#pragma unroll
    for (int mi = 0; mi < 8; mi++)
#pragma unroll
      for (int ni = 0; ni < 4; ni++)
        acc[mi][ni] = mfma16(aF[mi], bF[ni], acc[mi][ni]);
    __builtin_amdgcn_s_setprio(0);
    if (tt + 1 < NT) {  // boundary: ensure tile tt+1 resident for next iter
      if (tt + 4 <= NT)
        asm volatile("s_waitcnt vmcnt(8)" ::: "memory");
      else if (tt + 3 == NT)
        asm volatile("s_waitcnt vmcnt(4)" ::: "memory");
      else
        asm volatile("s_waitcnt vmcnt(0)" ::: "memory");
      __builtin_amdgcn_s_barrier();
      asm volatile("" ::: "memory");
    }
  }
}

// ---- fused 3-way projection GEMM: seg 0=Q(scaled) 1=K 2=V(transposed) ----
// M=8192, N=K=2048. Grid = 3 * 256 blocks of 512 threads.
// Epilogue routes through LDS (dead after K-loop; 128KB = 256x256 bf16 tile)
// so global stores are 16B fully-coalesced instead of 2B/8B scattered.
// LDS layout: Q/K row-major [row][col]; V transposed [d'][t'].
// Bank swizzle key (multiple of 32 -> preserves 8B/16B blocks and intra-
// block order): Q/K key=((row>>2)&15)<<5 on col*2; V key=(d'&15)<<5 on t'*2.
// Read-back chunk j of a row decodes exactly cols [8j,8j+8) in order.
__global__ __launch_bounds__(512, 2) void gemm256_proj3(
    const unsigned short* __restrict__ qb, const unsigned short* __restrict__ kb,
    const unsigned short* __restrict__ vb, const unsigned short* __restrict__ wqb,
    const unsigned short* __restrict__ wkb, const unsigned short* __restrict__ wvb,
    const float* __restrict__ bq, const float* __restrict__ bk,
    const float* __restrict__ bv, unsigned short* __restrict__ Qp,
    unsigned short* __restrict__ Kp, unsigned short* __restrict__ Vt,
    float qscale) {
  constexpr int K = 2048, N = 2048;
  __shared__ unsigned short lds[65536];  // 128 KiB
  const int seg = blockIdx.x >> 8;
  int inner = blockIdx.x & 255;
  inner = (inner & 7) * 32 + (inner >> 3);  // XCD swizzle, 256 % 8 == 0
  const int bm = inner >> 3, bn = inner & 7;

  const unsigned short* A = (seg == 0) ? qb : (seg == 1) ? kb : vb;
  const unsigned short* Bw = (seg == 0) ? wqb : (seg == 1) ? wkb : wvb;
  const float* bias = (seg == 0) ? bq : (seg == 1) ? bk : bv;

  floatx4 zero = {0.f, 0.f, 0.f, 0.f};
  floatx4 acc[8][4];
#pragma unroll
  for (int i = 0; i < 8; i++)
#pragma unroll
    for (int j = 0; j < 4; j++) acc[i][j] = zero;

  gemm256_core(A + (size_t)bm * 256 * K, Bw + (size_t)bn * 256 * K, lds, K, acc);

  const int t = threadIdx.x, l = t & 63, w = t >> 6;
  const int wm = w >> 2, wn = w & 3;
  const int lr = l & 15, lg = l >> 4;
  const float oscale = (seg == 0) ? qscale : 1.0f;
  char* ldsb = (char*)lds;

  __syncthreads();  // all waves done with frag reads; LDS buffers dead

  if (seg < 2) {
    // ---- write acc -> LDS [row][col] bf16, swizzled ----
#pragma unroll
    for (int ni = 0; ni < 4; ni++) {
      int col = wn * 64 + ni * 16 + lr;
      float bvv = bias[bn * 256 + col];
#pragma unroll
      for (int mi = 0; mi < 8; mi++) {
        int row0 = wm * 128 + mi * 16 + lg * 4;
#pragma unroll
        for (int r = 0; r < 4; r++) {
          int row = row0 + r;
          int off = row * 512 + ((col * 2) ^ (((row >> 2) & 15) << 5));
          *(unsigned short*)(ldsb + off) =
              f2bf((acc[mi][ni][r] + bvv) * oscale);
        }
      }
    }
    __syncthreads();
    // ---- coalesced read-back + 16B stores ----
    unsigned short* dst = (seg == 0) ? Qp : Kp;
#pragma unroll
    for (int i = 0; i < 16; i++) {
      int c = i * 512 + t;  // 8192 chunks of 16B
      int row = c >> 5, j = c & 31;
      int off = row * 512 + ((j * 16) ^ (((row >> 2) & 15) << 5));
      short8 v = *(const short8*)(ldsb + off);
      *(short8*)&dst[(size_t)(bm * 256 + row) * N + bn * 256 + j * 8] = v;
    }
  } else {
    // ---- write acc -> LDS transposed [d'][t'] bf16 (4 t' contiguous) ----
#pragma unroll
    for (int ni = 0; ni < 4; ni++) {
      int dp = wn * 64 + ni * 16 + lr;
      float bvv = bias[bn * 256 + dp];
#pragma unroll
      for (int mi = 0; mi < 8; mi++) {
        int tp0 = wm * 128 + mi * 16 + lg * 4;
        ushort4 v4;
        v4.x = f2bf(acc[mi][ni][0] + bvv);
        v4.y = f2bf(acc[mi][ni][1] + bvv);
        v4.z = f2bf(acc[mi][ni][2] + bvv);
        v4.w = f2bf(acc[mi][ni][3] + bvv);
        int off = dp * 512 + ((tp0 * 2) ^ ((dp & 15) << 5));
        *(ushort4*)(ldsb + off) = v4;
      }
    }
    __syncthreads();
    // ---- coalesced read-back + 16B stores into Vt [b][h][d][t] ----
    const int bb = bm >> 3;             // batch (2048 rows per b, 8 tiles)
    const int tb = (bm & 7) * 256;      // t-base within batch
#pragma unroll
    for (int i = 0; i < 16; i++) {
      int c = i * 512 + t;
      int dp = c >> 5, j = c & 31;
      int off = dp * 512 + ((j * 16) ^ ((dp & 15) << 5));
      short8 v = *(const short8*)(ldsb + off);
      int gcd = bn * 256 + dp;
      int h = gcd >> 7, d = gcd & 127;
      *(short8*)&Vt[((size_t)(bb * 16 + h) << 18) + (d << 11) + tb + j * 8] = v;
    }
  }
}

// ---- output projection GEMM, f32 out. M=8192, N=K=2048, 256 blocks. ----
__global__ __launch_bounds__(512, 2) void gemm256_out(
    const unsigned short* __restrict__ A, const unsigned short* __restrict__ Bw,
    const float* __restrict__ bias, float* __restrict__ outp) {
  constexpr int K = 2048, N = 2048;
  __shared__ unsigned short lds[65536];
  int inner = blockIdx.x;
  inner = (inner & 7) * 32 + (inner >> 3);  // XCD swizzle, 256 % 8 == 0
  const int bm = inner >> 3, bn = inner & 7;

  floatx4 zero = {0.f, 0.f, 0.f, 0.f};
  floatx4 acc[8][4];
#pragma unroll
  for (int i = 0; i < 8; i++)
#pragma unroll
    for (int j = 0; j < 4; j++) acc[i][j] = zero;

  gemm256_core(A + (size_t)bm * 256 * K, Bw + (size_t)bn * 256 * K, lds, K, acc);

  const int t = threadIdx.x, l = t & 63, w = t >> 6;
  const int wm = w >> 2, wn = w & 3;
  const int lr = l & 15, lg = l >> 4;
#pragma unroll
  for (int ni = 0; ni < 4; ni++) {
    int gc = bn * 256 + wn * 64 + ni * 16 + lr;
    float bvv = bias[gc];
#pragma unroll
    for (int mi = 0; mi < 8; mi++) {
      int gr0 = bm * 256 + wm * 128 + mi * 16 + lg * 4;
#pragma unroll
      for (int r = 0; r < 4; r++)
        outp[(size_t)(gr0 + r) * N + gc] = acc[mi][ni][r] + bvv;
    }
  }
}

// Causal flash attention, 8-wave blocks: each block = ONE bh, Q super-tile
// PAIR (x, 7-x) of 256 rows each -> uniform 36 tile-steps/block; grid 256 =
// exactly 1 block/CU (zero tail). 8 waves x 32 Q-rows, KVBLK=64, dbuf K/V
// prefetch, exp2-domain online softmax with defer-max (THR=8).
__global__ __launch_bounds__(512, 2) void attn_kernel(
    const unsigned short* __restrict__ Qp, const unsigned short* __restrict__ Kp,
    const unsigned short* __restrict__ Vt, unsigned short* __restrict__ Out) {
  constexpr int T = 2048, C = 2048;
  // ushort offsets: sK dbuf [2][64][128] @0, sV dbuf [2][128][64] @16384,
  // sP [8][32][64] @32768. Q-stage [256][128] @0 (pre-loop only).
  __shared__ unsigned short lds[49152];
  unsigned short* sP = lds + 32768;

  const int bid = blockIdx.x;
  const int swz = (bid & 7) * 32 + (bid >> 3);  // bijective, 256 % 8 == 0
  const int bh = swz >> 2;
  const int pr = swz & 3;                       // pair index 0..3
  const int b = bh >> 4, h = bh & 15;
  const int t = threadIdx.x, l = t & 63, w = t >> 6;
  const int lr = l & 15, lg = l >> 4, l7 = l & 7;

  const unsigned short* Kg = Kp + (size_t)(b * T) * C + h * 128;
  const unsigned short* Vg = Vt + ((size_t)bh << 18);  // [128][T]

  auto stage_kv = [&](int kb, int buf) {
    unsigned short* dK = lds + (buf ? 8192 : 0);
    unsigned short* dV = lds + 16384 + (buf ? 8192 : 0);
#pragma unroll
    for (int i = 0; i < 2; i++) {
      int c = t + i * 512;
      int row = c >> 4, cc = c & 15;
      LDS16(Kg + (size_t)(kb + row) * C + (cc ^ (row & 7)) * 8, &dK[c * 8]);
    }
#pragma unroll
    for (int i = 0; i < 2; i++) {
      int c = t + i * 512;
      int d = c >> 3, cc = c & 7;
      LDS16(Vg + (size_t)d * T + kb + (cc ^ (d & 7)) * 8, &dV[c * 8]);
    }
  };

  for (int seg = 0; seg < 2; seg++) {
    const int qs = seg ? pr : 7 - pr;  // heavy super-tile first
    const unsigned short* Qg = Qp + (size_t)(b * T + qs * 256) * C + h * 128;

    // ---- stage Q [256][128] into lds[0..32767], frags to regs ----
#pragma unroll
    for (int i = 0; i < 8; i++) {
      int c = t + i * 512;
      int row = c >> 4, cc = c & 15;
      LDS16(Qg + (size_t)row * C + cc * 8, &lds[c * 8]);
    }
    __syncthreads();
    const int qw = qs * 256 + w * 32;
    short8 qf[2][4];
#pragma unroll
    for (int mi = 0; mi < 2; mi++)
#pragma unroll
      for (int ks = 0; ks < 4; ks++)
        qf[mi][ks] = *(const short8*)&lds[(w * 32 + mi * 16 + lr) * 128 +
                                          ks * 32 + lg * 8];
    __syncthreads();  // all qf reads done before K/V staging overwrites

    floatx4 zero = {0.f, 0.f, 0.f, 0.f};
    floatx4 oacc[2][8];
#pragma unroll
    for (int i = 0; i < 2; i++)
#pragma unroll
      for (int j = 0; j < 8; j++) oacc[i][j] = zero;
    float mold[2][4], lsum[2][4];
#pragma unroll
    for (int i = 0; i < 2; i++)
#pragma unroll
      for (int r = 0; r < 4; r++) { mold[i][r] = -1e30f; lsum[i][r] = 0.f; }

    const int ntile = 4 * qs + 4;
    stage_kv(0, 0);
    __syncthreads();
    int cur = 0;
    for (int tile = 0; tile < ntile; tile++) {
      const int kbase = tile * 64;
      if (tile + 1 < ntile) stage_kv(kbase + 64, cur ^ 1);  // async prefetch
      const unsigned short* sK = lds + (cur ? 8192 : 0);
      const unsigned short* sV = lds + 16384 + (cur ? 8192 : 0);
      if (kbase <= qw + 31) {
        // ---- S = Q K^T ----
        floatx4 sc[2][4];
#pragma unroll
        for (int i = 0; i < 2; i++)
#pragma unroll
          for (int j = 0; j < 4; j++) sc[i][j] = zero;
        __builtin_amdgcn_s_setprio(1);
#pragma unroll
        for (int ks = 0; ks < 4; ks++) {
#pragma unroll
          for (int ni = 0; ni < 4; ni++) {
            int R = ni * 16 + lr;
            short8 bF = *(const short8*)&sK[R * 128 + ((ks * 4 + lg) ^ l7) * 8];
#pragma unroll
            for (int mi = 0; mi < 2; mi++)
              sc[mi][ni] = mfma16(qf[mi][ks], bF, sc[mi][ni]);
          }
        }
        __builtin_amdgcn_s_setprio(0);
        // ---- causal mask (diagonal tiles only) ----
        if (kbase + 63 > qw) {
#pragma unroll
          for (int mi = 0; mi < 2; mi++)
#pragma unroll
            for (int ni = 0; ni < 4; ni++)
#pragma unroll
              for (int r = 0; r < 4; r++) {
                int col = kbase + ni * 16 + lr;
                int row = qw + mi * 16 + lg * 4 + r;
                if (col > row) sc[mi][ni][r] = -1e30f;
              }
        }
        // ---- online softmax (exp2 domain, defer-max THR=8) ----
#pragma unroll
        for (int mi = 0; mi < 2; mi++) {
          float xr[4];
          int dok = 1;
#pragma unroll
          for (int r = 0; r < 4; r++) {
            float x = fmaxf(fmaxf(sc[mi][0][r], sc[mi][1][r]),
                            fmaxf(sc[mi][2][r], sc[mi][3][r]));
            x = fmaxf(x, __shfl_xor(x, 1));
            x = fmaxf(x, __shfl_xor(x, 2));
            x = fmaxf(x, __shfl_xor(x, 4));
            x = fmaxf(x, __shfl_xor(x, 8));
            xr[r] = x;
            dok &= (x - mold[mi][r] <= 8.0f) ? 1 : 0;
          }
          const bool defer = __all(dok);  // wave-uniform
          float al[4];
          if (!defer) {
#pragma unroll
            for (int r = 0; r < 4; r++) {
              float m2 = fmaxf(mold[mi][r], xr[r]);
              al[r] = __builtin_amdgcn_exp2f(mold[mi][r] - m2);
              mold[mi][r] = m2;
            }
          }
          float rs[4] = {0.f, 0.f, 0.f, 0.f};
#pragma unroll
          for (int ni = 0; ni < 4; ni++)
#pragma unroll
            for (int r = 0; r < 4; r++) {
              float p = __builtin_amdgcn_exp2f(sc[mi][ni][r] - mold[mi][r]);
              sc[mi][ni][r] = p;
              rs[r] += p;
            }
#pragma unroll
          for (int r = 0; r < 4; r++) {
            float s = rs[r];
            s += __shfl_xor(s, 1);
            s += __shfl_xor(s, 2);
            s += __shfl_xor(s, 4);
            s += __shfl_xor(s, 8);
            rs[r] = s;
          }
          if (!defer) {
#pragma unroll
            for (int r = 0; r < 4; r++)
              lsum[mi][r] = lsum[mi][r] * al[r] + rs[r];
#pragma unroll
            for (int ni = 0; ni < 8; ni++)
#pragma unroll
              for (int r = 0; r < 4; r++) oacc[mi][ni][r] *= al[r];
          } else {
#pragma unroll
            for (int r = 0; r < 4; r++) lsum[mi][r] += rs[r];
          }
          // P -> bf16 -> swizzled per-wave LDS
#pragma unroll
          for (int ni = 0; ni < 4; ni++)
#pragma unroll
            for (int r = 0; r < 4; r++) {
              int rr = mi * 16 + lg * 4 + r;
              int ch = (ni * 2 + ((l >> 3) & 1)) ^ (rr & 7);
              sP[w * 2048 + rr * 64 + ch * 8 + l7] = f2bf(sc[mi][ni][r]);
            }
        }
        // ---- O += P V ----
        __builtin_amdgcn_s_setprio(1);
#pragma unroll
        for (int ks = 0; ks < 2; ks++) {
          short8 pf[2];
#pragma unroll
          for (int mi = 0; mi < 2; mi++)
            pf[mi] = *(const short8*)&sP[w * 2048 + (mi * 16 + lr) * 64 +
                                         ((ks * 4 + lg) ^ l7) * 8];
#pragma unroll
          for (int ni = 0; ni < 8; ni++) {
            int d = ni * 16 + lr;
            short8 vF = *(const short8*)&sV[d * 64 + ((ks * 4 + lg) ^ l7) * 8];
#pragma unroll
            for (int mi = 0; mi < 2; mi++)
              oacc[mi][ni] = mfma16(pf[mi], vF, oacc[mi][ni]);
          }
        }
        __builtin_amdgcn_s_setprio(0);
      }
      __syncthreads();  // drains prefetch vmcnt; next buffer ready
      cur ^= 1;
    }
    // ---- epilogue: O/l -> bf16 row-major [B*T, C] (registers only; the
    // loop-final __syncthreads already fences LDS for next seg's Q-stage) ---
    unsigned short* Og = Out + (size_t)(b * T + qw) * C + h * 128;
#pragma unroll
    for (int mi = 0; mi < 2; mi++) {
      float rl[4];
#pragma unroll
      for (int r = 0; r < 4; r++) rl[r] = 1.0f / lsum[mi][r];
#pragma unroll
      for (int ni = 0; ni < 8; ni++)
#pragma unroll
        for (int r = 0; r < 4; r++)
          Og[(size_t)(mi * 16 + lg * 4 + r) * C + ni * 16 + lr] =
              f2bf(oacc[mi][ni][r] * rl[r]);
    }
  }
}

extern "C" void kernel_launch(void* const* d_in, const int* in_sizes, int n_in,
                              void* d_out, int out_size, void* d_ws,
                              size_t ws_size, hipStream_t stream) {
  const float* q = (const float*)d_in[0];
  const float* k = (const float*)d_in[1];
  const float* v = (const float*)d_in[2];
  const float* Wq = (const float*)d_in[3];
  const float* bq = (const float*)d_in[4];
  const float* Wk = (const float*)d_in[5];
  const float* bk = (const float*)d_in[6];
  const float* Wv = (const float*)d_in[7];
  const float* bv = (const float*)d_in[8];
  const float* Wo = (const float*)d_in[9];
  const float* bo = (const float*)d_in[10];

  const int B = 4, T = 2048, C = 2048;
  const size_t E = (size_t)B * T * C;   // 16,777,216
  const size_t WE = (size_t)C * C;      // 4,194,304
  unsigned short* ws = (unsigned short*)d_ws;
  unsigned short* qb = ws;              // bf16 q       [E]
  unsigned short* kb = ws + E;          // bf16 k
  unsigned short* vb = ws + 2 * E;      // bf16 v
  unsigned short* wqb = ws + 3 * E;     // bf16 weights [WE] x4
  unsigned short* wkb = wqb + WE;
  unsigned short* wvb = wqb + 2 * WE;
  unsigned short* wob = wqb + 3 * WE;
  unsigned short* Qp = ws + 4 * E;      // projected Q (pre-scaled)
  unsigned short* Kp = ws + 5 * E;      // projected K
  unsigned short* Vtb = ws + 6 * E;     // projected V, [B,H,D,T]
  unsigned short* attn = qb;            // alias: qb dead after projections
  // total workspace: 7*E*2 = 234,881,024 bytes

  Cvt7Args ca;
  ca.in[0] = q;  ca.out[0] = qb;  ca.n4[0] = (int)(E / 4);
  ca.in[1] = k;  ca.out[1] = kb;  ca.n4[1] = (int)(E / 4);
  ca.in[2] = v;  ca.out[2] = vb;  ca.n4[2] = (int)(E / 4);
  ca.in[3] = Wq; ca.out[3] = wqb; ca.n4[3] = (int)(WE / 4);
  ca.in[4] = Wk; ca.out[4] = wkb; ca.n4[4] = (int)(WE / 4);
  ca.in[5] = Wv; ca.out[5] = wvb; ca.n4[5] = (int)(WE / 4);
  ca.in[6] = Wo; ca.out[6] = wob; ca.n4[6] = (int)(WE / 4);
  cvt7_kernel<<<dim3(512, 7), 256, 0, stream>>>(ca);

  const float qscale = 1.4426950408889634f / sqrtf(128.0f);  // log2e/sqrt(D)
  gemm256_proj3<<<768, 512, 0, stream>>>(qb, kb, vb, wqb, wkb, wvb, bq, bk, bv,
                                         Qp, Kp, Vtb, qscale);

  attn_kernel<<<256, 512, 0, stream>>>(Qp, Kp, Vtb, attn);

  gemm256_out<<<256, 512, 0, stream>>>(attn, wob, bo, (float*)d_out);
}

// Round 15
// 491.897 us; speedup vs baseline: 1.1281x; 1.0418x over previous
//
#include <hip/hip_runtime.h>
#include <hip/hip_bf16.h>
#include <cmath>

// ToyMultiHeadAttention: B=4 T=2048 C=2048 H=16 D=128, causal.
// Pipeline: fused f32->bf16 convert | fused 3x NT proj GEMM (256^2 tile,
//           4-buffer counted-vmcnt pipeline, LDS-coalesced epilogue,
//           V writes transposed) | 8-wave balanced paired flash attention
//           (LDS-coalesced O epilogue) | NT out GEMM (256^2, f32,
//           2-half LDS-coalesced epilogue).
// Verified: R13 LDS epilogue on proj3 = WRITE 194->98MB, -17us. R14 extends
// the same pattern to attn (118MB vs 32 ideal) and gemm_out (2x f32 ampl).
// Failed probes, do not retry: R6 phase-split GEMM (-7%), R8 vmcnt(0)
// 2-tile coarsening (-11%), R9 attn KVBLK=128 (-5%), R10 256x128 2-blk/CU
// (-4%), R12 seg-looped proj3 (-12%).

#define DEV __device__ __forceinline__

typedef short short8 __attribute__((ext_vector_type(8)));
typedef float floatx4 __attribute__((ext_vector_type(4)));

// async global->LDS, 16B per lane; LDS dest must be uniform base + lane*16
#define LDS16(gp, lp)                                                        \
  __builtin_amdgcn_global_load_lds(                                          \
      (const __attribute__((address_space(1))) void*)(gp),                   \
      (__attribute__((address_space(3))) void*)(lp), 16, 0, 0)

DEV unsigned short f2bf(float f) {  // RNE f32->bf16 (inputs finite)
  unsigned u = __builtin_bit_cast(unsigned, f);
  u += 0x7fffu + ((u >> 16) & 1u);
  return (unsigned short)(u >> 16);
}

DEV floatx4 mfma16(short8 a, short8 b, floatx4 c) {
  return __builtin_amdgcn_mfma_f32_16x16x32_bf16(a, b, c, 0, 0, 0);
}

struct Cvt7Args {
  const float* in[7];
  unsigned short* out[7];
  int n4[7];
};

__global__ __launch_bounds__(256) void cvt7_kernel(Cvt7Args a) {
  const int s = blockIdx.y;
  const float* __restrict__ in = a.in[s];
  unsigned short* __restrict__ out = a.out[s];
  const int n4 = a.n4[s];
  int stride = gridDim.x * blockDim.x;
  for (int i = blockIdx.x * blockDim.x + threadIdx.x; i < n4; i += stride) {
    float4 v = reinterpret_cast<const float4*>(in)[i];
    ushort4 o;
    o.x = f2bf(v.x); o.y = f2bf(v.y); o.z = f2bf(v.z); o.w = f2bf(v.w);
    reinterpret_cast<ushort4*>(out)[i] = o;
  }
}

// ============ 256^2-tile NT GEMM core: C[256,256] = A[256,K] * B[256,K]^T ===
// 512 threads = 8 waves (2M x 4N). BK=32. LDS: 4 buffers x (A 16KB + B 16KB)
// = 128 KiB. Stage distance 3 tiles; one s_barrier + counted vmcnt(8) per
// tile (NEVER drain to 0 in steady state).
// LDS chunk swizzle ch ^= (row>>1)&3 on BOTH global source and ds_read
// (conflict-free: (row&1,(row>>1)&3) injective over 8 consecutive rows).
// Race-freedom: stage(t+3) targets buf[(t-1)&3], dead since the boundary
// barrier after tile t-1. Boundary after tile t: vmcnt(8) = stages(t+2,t+3)
// outstanding => stage(t+1) landed. On exit vmcnt==0.
DEV void gemm256_core(const unsigned short* __restrict__ aT,
                      const unsigned short* __restrict__ bT,
                      unsigned short* lds, const int K, floatx4 (&acc)[8][4]) {
  const int t = threadIdx.x;
  const int l = t & 63;
  const int w = t >> 6;
  const int wm = w >> 2, wn = w & 3;
  const int lr = l & 15, lg = l >> 4;
  const int NT = K >> 5;  // requires NT >= 3

  // staging: A tile 256x32 = 1024 16B-chunks, 2 per thread; same for B.
  const int rA0 = t >> 2;
  const int chA0 = (t & 3) ^ ((rA0 >> 1) & 3);
  const int rA1 = (t + 512) >> 2;
  const int chA1 = (t & 3) ^ ((rA1 >> 1) & 3);

  auto stage = [&](int kt, int buf) {
    unsigned short* dst = lds + buf * 16384;
    const unsigned short* ga = aT + kt * 32;
    const unsigned short* gb = bT + kt * 32;
    LDS16(ga + (size_t)rA0 * K + chA0 * 8, dst + t * 8);
    LDS16(ga + (size_t)rA1 * K + chA1 * 8, dst + (t + 512) * 8);
    LDS16(gb + (size_t)rA0 * K + chA0 * 8, dst + 8192 + t * 8);
    LDS16(gb + (size_t)rA1 * K + chA1 * 8, dst + 8192 + (t + 512) * 8);
  };

  // prologue: tiles 0,1,2 in flight; wait tile 0 (oldest 4 of 12 loads)
  stage(0, 0);
  stage(1, 1);
  stage(2, 2);
  asm volatile("s_waitcnt vmcnt(8)" ::: "memory");
  __builtin_amdgcn_s_barrier();
  asm volatile("" ::: "memory");

  for (int tt = 0; tt < NT; ++tt) {
    const unsigned short* lA = lds + (tt & 3) * 16384;
    const unsigned short* lB = lA + 8192;
    if (tt + 3 < NT) stage(tt + 3, (tt + 3) & 3);  // into buf[(tt-1)&3]
    short8 aF[8], bF[4];
#pragma unroll
    for (int ni = 0; ni < 4; ni++) {
      int row = wn * 64 + ni * 16 + lr;
      bF[ni] = *(const short8*)&lB[row * 32 + ((lg ^ ((row >> 1) & 3)) * 8)];
    }
#pragma unroll
    for (int mi = 0; mi < 8; mi++) {
      int row = wm * 128 + mi * 16 + lr;
      aF[mi] = *(const short8*)&lA[row * 32 + ((lg ^ ((row >> 1) & 3)) * 8)];
    }
    __builtin_amdgcn_s_setprio(1);
#pragma unroll
    for (int mi = 0; mi < 8; mi++)
#pragma unroll
      for (int ni = 0; ni < 4; ni++)
        acc[mi][ni] = mfma16(aF[mi], bF[ni], acc[mi][ni]);
    __builtin_amdgcn_s_setprio(0);
    if (tt + 1 < NT) {  // boundary: ensure tile tt+1 resident for next iter
      if (tt + 4 <= NT)
        asm volatile("s_waitcnt vmcnt(8)" ::: "memory");
      else if (tt + 3 == NT)
        asm volatile("s_waitcnt vmcnt(4)" ::: "memory");
      else
        asm volatile("s_waitcnt vmcnt(0)" ::: "memory");
      __builtin_amdgcn_s_barrier();
      asm volatile("" ::: "memory");
    }
  }
}

// ---- fused 3-way projection GEMM: seg 0=Q(scaled) 1=K 2=V(transposed) ----
// M=8192, N=K=2048. Grid = 3 * 256 blocks of 512 threads.
// Epilogue routes through LDS (dead after K-loop; 128KB = 256x256 bf16 tile)
// so global stores are 16B fully-coalesced. Bank swizzle key (multiple of 32
// -> preserves 8B/16B blocks and intra-block order): Q/K key=((row>>2)&15)<<5
// on col*2; V key=(d'&15)<<5 on t'*2. Read-back chunk j = cols [8j,8j+8).
__global__ __launch_bounds__(512, 2) void gemm256_proj3(
    const unsigned short* __restrict__ qb, const unsigned short* __restrict__ kb,
    const unsigned short* __restrict__ vb, const unsigned short* __restrict__ wqb,
    const unsigned short* __restrict__ wkb, const unsigned short* __restrict__ wvb,
    const float* __restrict__ bq, const float* __restrict__ bk,
    const float* __restrict__ bv, unsigned short* __restrict__ Qp,
    unsigned short* __restrict__ Kp, unsigned short* __restrict__ Vt,
    float qscale) {
  constexpr int K = 2048, N = 2048;
  __shared__ unsigned short lds[65536];  // 128 KiB
  const int seg = blockIdx.x >> 8;
  int inner = blockIdx.x & 255;
  inner = (inner & 7) * 32 + (inner >> 3);  // XCD swizzle, 256 % 8 == 0
  const int bm = inner >> 3, bn = inner & 7;

  const unsigned short* A = (seg == 0) ? qb : (seg == 1) ? kb : vb;
  const unsigned short* Bw = (seg == 0) ? wqb : (seg == 1) ? wkb : wvb;
  const float* bias = (seg == 0) ? bq : (seg == 1) ? bk : bv;

  floatx4 zero = {0.f, 0.f, 0.f, 0.f};
  floatx4 acc[8][4];
#pragma unroll
  for (int i = 0; i < 8; i++)
#pragma unroll
    for (int j = 0; j < 4; j++) acc[i][j] = zero;

  gemm256_core(A + (size_t)bm * 256 * K, Bw + (size_t)bn * 256 * K, lds, K, acc);

  const int t = threadIdx.x, l = t & 63, w = t >> 6;
  const int wm = w >> 2, wn = w & 3;
  const int lr = l & 15, lg = l >> 4;
  const float oscale = (seg == 0) ? qscale : 1.0f;
  char* ldsb = (char*)lds;

  __syncthreads();  // all waves done with frag reads; LDS buffers dead

  if (seg < 2) {
    // ---- write acc -> LDS [row][col] bf16, swizzled ----
#pragma unroll
    for (int ni = 0; ni < 4; ni++) {
      int col = wn * 64 + ni * 16 + lr;
      float bvv = bias[bn * 256 + col];
#pragma unroll
      for (int mi = 0; mi < 8; mi++) {
        int row0 = wm * 128 + mi * 16 + lg * 4;
#pragma unroll
        for (int r = 0; r < 4; r++) {
          int row = row0 + r;
          int off = row * 512 + ((col * 2) ^ (((row >> 2) & 15) << 5));
          *(unsigned short*)(ldsb + off) =
              f2bf((acc[mi][ni][r] + bvv) * oscale);
        }
      }
    }
    __syncthreads();
    // ---- coalesced read-back + 16B stores ----
    unsigned short* dst = (seg == 0) ? Qp : Kp;
#pragma unroll
    for (int i = 0; i < 16; i++) {
      int c = i * 512 + t;  // 8192 chunks of 16B
      int row = c >> 5, j = c & 31;
      int off = row * 512 + ((j * 16) ^ (((row >> 2) & 15) << 5));
      short8 v = *(const short8*)(ldsb + off);
      *(short8*)&dst[(size_t)(bm * 256 + row) * N + bn * 256 + j * 8] = v;
    }
  } else {
    // ---- write acc -> LDS transposed [d'][t'] bf16 (4 t' contiguous) ----
#pragma unroll
    for (int ni = 0; ni < 4; ni++) {
      int dp = wn * 64 + ni * 16 + lr;
      float bvv = bias[bn * 256 + dp];
#pragma unroll
      for (int mi = 0; mi < 8; mi++) {
        int tp0 = wm * 128 + mi * 16 + lg * 4;
        ushort4 v4;
        v4.x = f2bf(acc[mi][ni][0] + bvv);
        v4.y = f2bf(acc[mi][ni][1] + bvv);
        v4.z = f2bf(acc[mi][ni][2] + bvv);
        v4.w = f2bf(acc[mi][ni][3] + bvv);
        int off = dp * 512 + ((tp0 * 2) ^ ((dp & 15) << 5));
        *(ushort4*)(ldsb + off) = v4;
      }
    }
    __syncthreads();
    // ---- coalesced read-back + 16B stores into Vt [b][h][d][t] ----
    const int bb = bm >> 3;             // batch (2048 rows per b, 8 tiles)
    const int tb = (bm & 7) * 256;      // t-base within batch
#pragma unroll
    for (int i = 0; i < 16; i++) {
      int c = i * 512 + t;
      int dp = c >> 5, j = c & 31;
      int off = dp * 512 + ((j * 16) ^ ((dp & 15) << 5));
      short8 v = *(const short8*)(ldsb + off);
      int gcd = bn * 256 + dp;
      int h = gcd >> 7, d = gcd & 127;
      *(short8*)&Vt[((size_t)(bb * 16 + h) << 18) + (d << 11) + tb + j * 8] = v;
    }
  }
}

// ---- output projection GEMM, f32 out. M=8192, N=K=2048, 256 blocks. ----
// Epilogue via LDS in TWO 128-row halves (128 rows x 1024B = 128KB exactly):
// waves of half 'wm' write f32 swizzled (key=((row>>2)&7)<<5, multiple of 32
// -> 16B blocks preserved; chunk j = cols [4j,4j+4)), then all threads
// read back float4 and store 16B fully-coalesced (1KB contiguous per row).
__global__ __launch_bounds__(512, 2) void gemm256_out(
    const unsigned short* __restrict__ A, const unsigned short* __restrict__ Bw,
    const float* __restrict__ bias, float* __restrict__ outp) {
  constexpr int K = 2048, N = 2048;
  __shared__ unsigned short lds[65536];
  int inner = blockIdx.x;
  inner = (inner & 7) * 32 + (inner >> 3);  // XCD swizzle, 256 % 8 == 0
  const int bm = inner >> 3, bn = inner & 7;

  floatx4 zero = {0.f, 0.f, 0.f, 0.f};
  floatx4 acc[8][4];
#pragma unroll
  for (int i = 0; i < 8; i++)
#pragma unroll
    for (int j = 0; j < 4; j++) acc[i][j] = zero;

  gemm256_core(A + (size_t)bm * 256 * K, Bw + (size_t)bn * 256 * K, lds, K, acc);

  const int t = threadIdx.x, l = t & 63, w = t >> 6;
  const int wm = w >> 2, wn = w & 3;
  const int lr = l & 15, lg = l >> 4;
  char* ldsb = (char*)lds;

  __syncthreads();  // LDS buffers dead after core

#pragma unroll
  for (int half = 0; half < 2; ++half) {
    if (wm == half) {
#pragma unroll
      for (int ni = 0; ni < 4; ni++) {
        int col = wn * 64 + ni * 16 + lr;
        float bvv = bias[bn * 256 + col];
#pragma unroll
        for (int mi = 0; mi < 8; mi++) {
          int lrow0 = mi * 16 + lg * 4;  // 0..127 within half
#pragma unroll
          for (int r = 0; r < 4; r++) {
            int row = lrow0 + r;
            int off = row * 1024 + ((col * 4) ^ (((row >> 2) & 7) << 5));
            *(float*)(ldsb + off) = acc[mi][ni][r] + bvv;
          }
        }
      }
    }
    __syncthreads();
#pragma unroll
    for (int i = 0; i < 16; i++) {
      int c = i * 512 + t;  // 8192 chunks of 16B = 128KB
      int row = c >> 6, j = c & 63;
      int off = row * 1024 + ((j * 16) ^ (((row >> 2) & 7) << 5));
      float4 v = *(const float4*)(ldsb + off);
      *(float4*)&outp[(size_t)(bm * 256 + half * 128 + row) * N + bn * 256 +
                      j * 4] = v;
    }
    __syncthreads();
  }
}

// Causal flash attention, 8-wave blocks: each block = ONE bh, Q super-tile
// PAIR (x, 7-x) of 256 rows each -> uniform 36 tile-steps/block; grid 256 =
// exactly 1 block/CU (zero tail). 8 waves x 32 Q-rows, KVBLK=64, dbuf K/V
// prefetch, exp2-domain online softmax with defer-max (THR=8).
// O epilogue via LDS [256][128] bf16 (64KB, key=((row>>2)&7)<<5) ->
// coalesced 16B stores (256B contiguous per row); WRITE was 118MB vs 32MB
// ideal with the direct ushort stores.
__global__ __launch_bounds__(512, 2) void attn_kernel(
    const unsigned short* __restrict__ Qp, const unsigned short* __restrict__ Kp,
    const unsigned short* __restrict__ Vt, unsigned short* __restrict__ Out) {
  constexpr int T = 2048, C = 2048;
  // ushort offsets: sK dbuf [2][64][128] @0, sV dbuf [2][128][64] @16384,
  // sP [8][32][64] @32768. Q-stage [256][128] @0 (pre-loop only); O-stage
  // [256][128] @0 (post-loop only).
  __shared__ unsigned short lds[49152];
  unsigned short* sP = lds + 32768;

  const int bid = blockIdx.x;
  const int swz = (bid & 7) * 32 + (bid >> 3);  // bijective, 256 % 8 == 0
  const int bh = swz >> 2;
  const int pr = swz & 3;                       // pair index 0..3
  const int b = bh >> 4, h = bh & 15;
  const int t = threadIdx.x, l = t & 63, w = t >> 6;
  const int lr = l & 15, lg = l >> 4, l7 = l & 7;

  const unsigned short* Kg = Kp + (size_t)(b * T) * C + h * 128;
  const unsigned short* Vg = Vt + ((size_t)bh << 18);  // [128][T]

  auto stage_kv = [&](int kb, int buf) {
    unsigned short* dK = lds + (buf ? 8192 : 0);
    unsigned short* dV = lds + 16384 + (buf ? 8192 : 0);
#pragma unroll
    for (int i = 0; i < 2; i++) {
      int c = t + i * 512;
      int row = c >> 4, cc = c & 15;
      LDS16(Kg + (size_t)(kb + row) * C + (cc ^ (row & 7)) * 8, &dK[c * 8]);
    }
#pragma unroll
    for (int i = 0; i < 2; i++) {
      int c = t + i * 512;
      int d = c >> 3, cc = c & 7;
      LDS16(Vg + (size_t)d * T + kb + (cc ^ (d & 7)) * 8, &dV[c * 8]);
    }
  };

  for (int seg = 0; seg < 2; seg++) {
    const int qs = seg ? pr : 7 - pr;  // heavy super-tile first
    const unsigned short* Qg = Qp + (size_t)(b * T + qs * 256) * C + h * 128;

    // ---- stage Q [256][128] into lds[0..32767], frags to regs ----
#pragma unroll
    for (int i = 0; i < 8; i++) {
      int c = t + i * 512;
      int row = c >> 4, cc = c & 15;
      LDS16(Qg + (size_t)row * C + cc * 8, &lds[c * 8]);
    }
    __syncthreads();
    const int qw = qs * 256 + w * 32;
    short8 qf[2][4];
#pragma unroll
    for (int mi = 0; mi < 2; mi++)
#pragma unroll
      for (int ks = 0; ks < 4; ks++)
        qf[mi][ks] = *(const short8*)&lds[(w * 32 + mi * 16 + lr) * 128 +
                                          ks * 32 + lg * 8];
    __syncthreads();  // all qf reads done before K/V staging overwrites

    floatx4 zero = {0.f, 0.f, 0.f, 0.f};
    floatx4 oacc[2][8];
#pragma unroll
    for (int i = 0; i < 2; i++)
#pragma unroll
      for (int j = 0; j < 8; j++) oacc[i][j] = zero;
    float mold[2][4], lsum[2][4];
#pragma unroll
    for (int i = 0; i < 2; i++)
#pragma unroll
      for (int r = 0; r < 4; r++) { mold[i][r] = -1e30f; lsum[i][r] = 0.f; }

    const int ntile = 4 * qs + 4;
    stage_kv(0, 0);
    __syncthreads();
    int cur = 0;
    for (int tile = 0; tile < ntile; tile++) {
      const int kbase = tile * 64;
      if (tile + 1 < ntile) stage_kv(kbase + 64, cur ^ 1);  // async prefetch
      const unsigned short* sK = lds + (cur ? 8192 : 0);
      const unsigned short* sV = lds + 16384 + (cur ? 8192 : 0);
      if (kbase <= qw + 31) {
        // ---- S = Q K^T ----
        floatx4 sc[2][4];
#pragma unroll
        for (int i = 0; i < 2; i++)
#pragma unroll
          for (int j = 0; j < 4; j++) sc[i][j] = zero;
        __builtin_amdgcn_s_setprio(1);
#pragma unroll
        for (int ks = 0; ks < 4; ks++) {
#pragma unroll
          for (int ni = 0; ni < 4; ni++) {
            int R = ni * 16 + lr;
            short8 bF = *(const short8*)&sK[R * 128 + ((ks * 4 + lg) ^ l7) * 8];
#pragma unroll
            for (int mi = 0; mi < 2; mi++)
              sc[mi][ni] = mfma16(qf[mi][ks], bF, sc[mi][ni]);
          }
        }
        __builtin_amdgcn_s_setprio(0);
        // ---- causal mask (diagonal tiles only) ----
        if (kbase + 63 > qw) {
#pragma unroll
          for (int mi = 0; mi < 2; mi++)
#pragma unroll
            for (int ni = 0; ni < 4; ni++)
#pragma unroll
              for (int r = 0; r < 4; r++) {
                int col = kbase + ni * 16 + lr;
                int row = qw + mi * 16 + lg * 4 + r;
                if (col > row) sc[mi][ni][r] = -1e30f;
              }
        }
        // ---- online softmax (exp2 domain, defer-max THR=8) ----
#pragma unroll
        for (int mi = 0; mi < 2; mi++) {
          float xr[4];
          int dok = 1;
#pragma unroll
          for (int r = 0; r < 4; r++) {
            float x = fmaxf(fmaxf(sc[mi][0][r], sc[mi][1][r]),
                            fmaxf(sc[mi][2][r], sc[mi][3][r]));
            x = fmaxf(x, __shfl_xor(x, 1));
            x = fmaxf(x, __shfl_xor(x, 2));
            x = fmaxf(x, __shfl_xor(x, 4));
            x = fmaxf(x, __shfl_xor(x, 8));
            xr[r] = x;
            dok &= (x - mold[mi][r] <= 8.0f) ? 1 : 0;
          }
          const bool defer = __all(dok);  // wave-uniform
          float al[4];
          if (!defer) {
#pragma unroll
            for (int r = 0; r < 4; r++) {
              float m2 = fmaxf(mold[mi][r], xr[r]);
              al[r] = __builtin_amdgcn_exp2f(mold[mi][r] - m2);
              mold[mi][r] = m2;
            }
          }
          float rs[4] = {0.f, 0.f, 0.f, 0.f};
#pragma unroll
          for (int ni = 0; ni < 4; ni++)
#pragma unroll
            for (int r = 0; r < 4; r++) {
              float p = __builtin_amdgcn_exp2f(sc[mi][ni][r] - mold[mi][r]);
              sc[mi][ni][r] = p;
              rs[r] += p;
            }
#pragma unroll
          for (int r = 0; r < 4; r++) {
            float s = rs[r];
            s += __shfl_xor(s, 1);
            s += __shfl_xor(s, 2);
            s += __shfl_xor(s, 4);
            s += __shfl_xor(s, 8);
            rs[r] = s;
          }
          if (!defer) {
#pragma unroll
            for (int r = 0; r < 4; r++)
              lsum[mi][r] = lsum[mi][r] * al[r] + rs[r];
#pragma unroll
            for (int ni = 0; ni < 8; ni++)
#pragma unroll
              for (int r = 0; r < 4; r++) oacc[mi][ni][r] *= al[r];
          } else {
#pragma unroll
            for (int r = 0; r < 4; r++) lsum[mi][r] += rs[r];
          }
          // P -> bf16 -> swizzled per-wave LDS
#pragma unroll
          for (int ni = 0; ni < 4; ni++)
#pragma unroll
            for (int r = 0; r < 4; r++) {
              int rr = mi * 16 + lg * 4 + r;
              int ch = (ni * 2 + ((l >> 3) & 1)) ^ (rr & 7);
              sP[w * 2048 + rr * 64 + ch * 8 + l7] = f2bf(sc[mi][ni][r]);
            }
        }
        // ---- O += P V ----
        __builtin_amdgcn_s_setprio(1);
#pragma unroll
        for (int ks = 0; ks < 2; ks++) {
          short8 pf[2];
#pragma unroll
          for (int mi = 0; mi < 2; mi++)
            pf[mi] = *(const short8*)&sP[w * 2048 + (mi * 16 + lr) * 64 +
                                         ((ks * 4 + lg) ^ l7) * 8];
#pragma unroll
          for (int ni = 0; ni < 8; ni++) {
            int d = ni * 16 + lr;
            short8 vF = *(const short8*)&sV[d * 64 + ((ks * 4 + lg) ^ l7) * 8];
#pragma unroll
            for (int mi = 0; mi < 2; mi++)
              oacc[mi][ni] = mfma16(pf[mi], vF, oacc[mi][ni]);
          }
        }
        __builtin_amdgcn_s_setprio(0);
      }
      __syncthreads();  // drains prefetch vmcnt; next buffer ready
      cur ^= 1;
    }
    // ---- epilogue: O/l -> LDS [256][128] bf16 swizzled -> coalesced 16B
    // stores. LDS fully dead after the loop-final __syncthreads. ----
    {
      char* ldsb = (char*)lds;
#pragma unroll
      for (int mi = 0; mi < 2; mi++) {
        float rl[4];
#pragma unroll
        for (int r = 0; r < 4; r++) rl[r] = 1.0f / lsum[mi][r];
#pragma unroll
        for (int ni = 0; ni < 8; ni++) {
          int col = ni * 16 + lr;
#pragma unroll
          for (int r = 0; r < 4; r++) {
            int row = w * 32 + mi * 16 + lg * 4 + r;
            int off = row * 256 + ((col * 2) ^ (((row >> 2) & 7) << 5));
            *(unsigned short*)(ldsb + off) = f2bf(oacc[mi][ni][r] * rl[r]);
          }
        }
      }
      __syncthreads();
      unsigned short* Og = Out + (size_t)(b * T + qs * 256) * C + h * 128;
#pragma unroll
      for (int i = 0; i < 8; i++) {
        int c = i * 512 + t;  // 4096 chunks of 16B (256 rows x 16)
        int row = c >> 4, j = c & 15;
        int off = row * 256 + ((j * 16) ^ (((row >> 2) & 7) << 5));
        short8 v = *(const short8*)(ldsb + off);
        *(short8*)&Og[(size_t)row * C + j * 8] = v;
      }
      __syncthreads();  // O region reused by next seg's Q staging
    }
  }
}

extern "C" void kernel_launch(void* const* d_in, const int* in_sizes, int n_in,
                              void* d_out, int out_size, void* d_ws,
                              size_t ws_size, hipStream_t stream) {
  const float* q = (const float*)d_in[0];
  const float* k = (const float*)d_in[1];
  const float* v = (const float*)d_in[2];
  const float* Wq = (const float*)d_in[3];
  const float* bq = (const float*)d_in[4];
  const float* Wk = (const float*)d_in[5];
  const float* bk = (const float*)d_in[6];
  const float* Wv = (const float*)d_in[7];
  const float* bv = (const float*)d_in[8];
  const float* Wo = (const float*)d_in[9];
  const float* bo = (const float*)d_in[10];

  const int B = 4, T = 2048, C = 2048;
  const size_t E = (size_t)B * T * C;   // 16,777,216
  const size_t WE = (size_t)C * C;      // 4,194,304
  unsigned short* ws = (unsigned short*)d_ws;
  unsigned short* qb = ws;              // bf16 q       [E]
  unsigned short* kb = ws + E;          // bf16 k
  unsigned short* vb = ws + 2 * E;      // bf16 v
  unsigned short* wqb = ws + 3 * E;     // bf16 weights [WE] x4
  unsigned short* wkb = wqb + WE;
  unsigned short* wvb = wqb + 2 * WE;
  unsigned short* wob = wqb + 3 * WE;
  unsigned short* Qp = ws + 4 * E;      // projected Q (pre-scaled)
  unsigned short* Kp = ws + 5 * E;      // projected K
  unsigned short* Vtb = ws + 6 * E;     // projected V, [B,H,D,T]
  unsigned short* attn = qb;            // alias: qb dead after projections
  // total workspace: 7*E*2 = 234,881,024 bytes

  Cvt7Args ca;
  ca.in[0] = q;  ca.out[0] = qb;  ca.n4[0] = (int)(E / 4);
  ca.in[1] = k;  ca.out[1] = kb;  ca.n4[1] = (int)(E / 4);
  ca.in[2] = v;  ca.out[2] = vb;  ca.n4[2] = (int)(E / 4);
  ca.in[3] = Wq; ca.out[3] = wqb; ca.n4[3] = (int)(WE / 4);
  ca.in[4] = Wk; ca.out[4] = wkb; ca.n4[4] = (int)(WE / 4);
  ca.in[5] = Wv; ca.out[5] = wvb; ca.n4[5] = (int)(WE / 4);
  ca.in[6] = Wo; ca.out[6] = wob; ca.n4[6] = (int)(WE / 4);
  cvt7_kernel<<<dim3(512, 7), 256, 0, stream>>>(ca);

  const float qscale = 1.4426950408889634f / sqrtf(128.0f);  // log2e/sqrt(D)
  gemm256_proj3<<<768, 512, 0, stream>>>(qb, kb, vb, wqb, wkb, wvb, bq, bk, bv,
                                         Qp, Kp, Vtb, qscale);

  attn_kernel<<<256, 512, 0, stream>>>(Qp, Kp, Vtb, attn);

  gemm256_out<<<256, 512, 0, stream>>>(attn, wob, bo, (float*)d_out);
}